// Round 3
// baseline (608.036 us; speedup 1.0000x reference)
//
#include <hip/hip_runtime.h>

typedef __attribute__((ext_vector_type(8))) __bf16 bf16x8;
typedef __attribute__((ext_vector_type(4))) __bf16 bf16x4;
typedef __attribute__((ext_vector_type(4))) float f32x4;

#define DEV static __device__ __forceinline__

DEV float fast_rcp(float x) { return __builtin_amdgcn_rcpf(x); }
DEV float sigm(float x) { return fast_rcp(1.f + __expf(-x)); }
DEV float siluf(float x) { return x * sigm(x); }
DEV float softplusf(float x) { return x > 20.f ? x : __logf(1.f + __expf(x)); }

// ---------------- K0: 1x1 conv projection (96->192) + BN, write v (BL,192) fp32 ----
__global__ __launch_bounds__(192) void k_proj_bn(
    const float* __restrict__ x, const float* __restrict__ pw,
    const float* __restrict__ pb, const float* __restrict__ bng,
    const float* __restrict__ bnb, const float* __restrict__ bnm,
    const float* __restrict__ bnv, float* __restrict__ v)
{
  __shared__ float pwT[96 * 192];
  __shared__ float sc[192], sh[192];
  __shared__ float xs[96];
  const int tid = threadIdx.x;
  for (int idx = tid; idx < 96 * 192; idx += 192) {
    int o = idx / 96, c = idx % 96;
    pwT[c * 192 + o] = pw[idx];
  }
  {
    float rstd = rsqrtf(bnv[tid] + 1e-5f);
    float s = rstd * bng[tid];
    sc[tid] = s;
    sh[tid] = (pb[tid] - bnm[tid]) * s + bnb[tid];
  }
  const int p0 = blockIdx.x * 32;
  for (int p = 0; p < 32; ++p) {
    const int pix = p0 + p;
    const int b = pix / 3136, l = pix % 3136;
    __syncthreads();
    if (tid < 96) xs[tid] = x[(b * 96 + tid) * 3136 + l];
    __syncthreads();
    float acc = 0.f;
#pragma unroll 8
    for (int c = 0; c < 96; ++c) acc += xs[c] * pwT[c * 192 + tid];
    v[pix * 192 + tid] = acc * sc[tid] + sh[tid];
  }
}

// ---------------- generic MFMA GEMM: O[r,e] = sum_d A[r,d]*W[e,d] ----------------
constexpr int EPI_XZ = 0, EPI_G2 = 1, EPI_RES = 2, EPI_RES_SKIP = 3, EPI_OUT2 = 4;

template <int LNMODE, int EPI>
__global__ __launch_bounds__(256) void k_gemm(
    const float* __restrict__ A, const float* __restrict__ W,
    const float* __restrict__ bias, float* __restrict__ O,
    int M, int K, int Nvalid,
    const float* __restrict__ lng, const float* __restrict__ lnb,
    const float* __restrict__ Wdt, const float* __restrict__ bdt,
    float* __restrict__ dtbuf, float* __restrict__ bcbuf,
    float* __restrict__ oflt, int Lseq)
{
  constexpr int SA = 200;  // LDS row stride in bf16 (192+8)
  __shared__ __bf16 As[64 * SA];
  __shared__ __bf16 Ws[64 * SA];
  __shared__ float lngS[192], lnbS[192];
  const int tid = threadIdx.x;
  const int r0 = blockIdx.x * 64;
  const int col0 = blockIdx.y * 64;
  const int lane = tid & 63, wv = tid >> 6;
  const int rh = wv >> 1, ch = wv & 1;
  const int lm = lane & 15, quad = lane >> 4;

  if constexpr (LNMODE == 1) {
    if (tid < 192) { lngS[tid] = lng[tid]; lnbS[tid] = lnb[tid]; }
    __syncthreads();
  }

  f32x4 acc[2][2] = {};
  const int nkp = K / 192;
  for (int kp = 0; kp < nkp; ++kp) {
    if (kp) __syncthreads();
    // ---- stage A (fp32 -> bf16, optional LN) ----
    {
      const int row = tid >> 2, part = tid & 3;
      const int grow = r0 + row;
      const int cbase = part * 48;
      float4 tv[12];
      if (grow < M) {
#pragma unroll
        for (int j = 0; j < 12; ++j)
          tv[j] = *(const float4*)(A + (size_t)grow * K + kp * 192 + cbase + j * 4);
      } else {
#pragma unroll
        for (int j = 0; j < 12; ++j) tv[j] = make_float4(0.f, 0.f, 0.f, 0.f);
      }
      if constexpr (LNMODE == 1) {
        float s = 0.f, sq = 0.f;
#pragma unroll
        for (int j = 0; j < 12; ++j) {
          s += tv[j].x + tv[j].y + tv[j].z + tv[j].w;
          sq += tv[j].x * tv[j].x + tv[j].y * tv[j].y + tv[j].z * tv[j].z + tv[j].w * tv[j].w;
        }
        s += __shfl_xor(s, 1); s += __shfl_xor(s, 2);
        sq += __shfl_xor(sq, 1); sq += __shfl_xor(sq, 2);
        const float mean = s * (1.f / 192.f);
        const float rstd = rsqrtf(sq * (1.f / 192.f) - mean * mean + 1e-5f);
#pragma unroll
        for (int j = 0; j < 12; ++j) {
          const int c = cbase + j * 4;
          tv[j].x = (tv[j].x - mean) * rstd * lngS[c + 0] + lnbS[c + 0];
          tv[j].y = (tv[j].y - mean) * rstd * lngS[c + 1] + lnbS[c + 1];
          tv[j].z = (tv[j].z - mean) * rstd * lngS[c + 2] + lnbS[c + 2];
          tv[j].w = (tv[j].w - mean) * rstd * lngS[c + 3] + lnbS[c + 3];
        }
      }
#pragma unroll
      for (int j = 0; j < 12; ++j) {
        bf16x4 o;
        o[0] = (__bf16)tv[j].x; o[1] = (__bf16)tv[j].y;
        o[2] = (__bf16)tv[j].z; o[3] = (__bf16)tv[j].w;
        *(bf16x4*)(&As[row * SA + cbase + j * 4]) = o;
      }
    }
    // ---- stage W (fp32 global row-major (N,K) -> bf16 LDS) ----
#pragma unroll
    for (int it = 0; it < 12; ++it) {
      const int idx = tid + it * 256;          // 0..3071
      const int wr = idx / 48, c4 = (idx % 48) * 4;
      const int gw = col0 + wr;
      float4 t = make_float4(0.f, 0.f, 0.f, 0.f);
      if (gw < Nvalid) t = *(const float4*)(W + (size_t)gw * K + kp * 192 + c4);
      bf16x4 o;
      o[0] = (__bf16)t.x; o[1] = (__bf16)t.y; o[2] = (__bf16)t.z; o[3] = (__bf16)t.w;
      *(bf16x4*)(&Ws[wr * SA + c4]) = o;
    }
    __syncthreads();
    // ---- mfma 6 k-steps ----
#pragma unroll
    for (int ks = 0; ks < 6; ++ks) {
      const int kb = ks * 32 + quad * 8;
      bf16x8 a0 = *(const bf16x8*)(&As[(rh * 32 + lm) * SA + kb]);
      bf16x8 a1 = *(const bf16x8*)(&As[(rh * 32 + 16 + lm) * SA + kb]);
      bf16x8 b0 = *(const bf16x8*)(&Ws[(ch * 32 + lm) * SA + kb]);
      bf16x8 b1 = *(const bf16x8*)(&Ws[(ch * 32 + 16 + lm) * SA + kb]);
      acc[0][0] = __builtin_amdgcn_mfma_f32_16x16x32_bf16(a0, b0, acc[0][0], 0, 0, 0);
      acc[0][1] = __builtin_amdgcn_mfma_f32_16x16x32_bf16(a0, b1, acc[0][1], 0, 0, 0);
      acc[1][0] = __builtin_amdgcn_mfma_f32_16x16x32_bf16(a1, b0, acc[1][0], 0, 0, 0);
      acc[1][1] = __builtin_amdgcn_mfma_f32_16x16x32_bf16(a1, b1, acc[1][1], 0, 0, 0);
    }
  }

  // ---- epilogue ----
  if constexpr (EPI == EPI_G2) {
    __shared__ float dtlS[64 * 12];
    __shared__ float wdtS[12 * 384];
#pragma unroll
    for (int ti = 0; ti < 2; ++ti)
#pragma unroll
      for (int tj = 0; tj < 2; ++tj) {
        const int colt = ch * 32 + tj * 16 + lm;
#pragma unroll
        for (int j = 0; j < 4; ++j) {
          const int rowt = rh * 32 + ti * 16 + quad * 4 + j;
          const int grow = r0 + rowt;
          const float val = acc[ti][tj][j];
          if (colt < 12) dtlS[rowt * 12 + colt] = val;            // dtl
          else if (colt < 44 && grow < M)
            bcbuf[(size_t)grow * 32 + (colt - 12)] = val;         // Bm(0..15), Cm(16..31)
        }
      }
    for (int idx = tid; idx < 12 * 384; idx += 256) {
      const int e = idx / 12, r = idx % 12;
      wdtS[r * 384 + e] = Wdt[idx];
    }
    __syncthreads();
    for (int it = 0; it < 96; ++it) {
      const int flat = tid + it * 256;
      const int rr = flat / 384, e = flat % 384;
      const int grow = r0 + rr;
      if (grow < M) {
        float a = bdt[e];
#pragma unroll
        for (int r = 0; r < 12; ++r) a += dtlS[rr * 12 + r] * wdtS[r * 384 + e];
        dtbuf[(size_t)grow * 384 + e] = softplusf(a);
      }
    }
  } else {
#pragma unroll
    for (int ti = 0; ti < 2; ++ti)
#pragma unroll
      for (int tj = 0; tj < 2; ++tj) {
        const int colt = ch * 32 + tj * 16 + lm;
        const int gcol = col0 + colt;
        const float bv = bias[gcol];
#pragma unroll
        for (int j = 0; j < 4; ++j) {
          const int rowt = rh * 32 + ti * 16 + quad * 4 + j;
          const int grow = r0 + rowt;
          if (grow >= M) continue;
          const float val = acc[ti][tj][j] + bv;
          if constexpr (EPI == EPI_XZ) {
            O[(size_t)grow * 768 + gcol] = val;
          } else if constexpr (EPI == EPI_RES) {
            O[(size_t)grow * 192 + gcol] += val;
          } else if constexpr (EPI == EPI_RES_SKIP) {
            const float nv = O[(size_t)grow * 192 + gcol] + val;
            O[(size_t)grow * 192 + gcol] = nv;
            const int b = grow / 3136, l = grow % 3136;
            oflt[b * 602112 + gcol * 3136 + l] = nv;              // skip (B,192,56,56) fp32
          } else {  // EPI_OUT2
            const int b = grow / 784, l = grow % 784;
            oflt[b * 150528 + gcol * 784 + l] = val;              // out0 (B,192,28,28) fp32
          }
        }
      }
  }
}

// ---------------- depthwise causal conv K=4 + silu ----------------
__global__ __launch_bounds__(256) void k_conv(
    const float* __restrict__ xz, float* __restrict__ xi,
    const float* __restrict__ cw, const float* __restrict__ cb,
    int Lseq, int total)
{
  const int idx = blockIdx.x * 256 + threadIdx.x;
  if (idx >= total) return;
  const int e = idx % 384;
  const int row = idx / 384;
  const int l = row % Lseq;
  const float4 w4 = *(const float4*)(cw + e * 4);
  float acc = cb[e];
  if (l >= 3) acc += xz[(size_t)(row - 3) * 768 + e] * w4.x;
  if (l >= 2) acc += xz[(size_t)(row - 2) * 768 + e] * w4.y;
  if (l >= 1) acc += xz[(size_t)(row - 1) * 768 + e] * w4.z;
  acc += xz[(size_t)row * 768 + e] * w4.w;
  xi[idx] = siluf(acc);
}

// ---------------- 2x2 maxpool ----------------
__global__ __launch_bounds__(256) void k_pool(const float* __restrict__ v, float* __restrict__ vp)
{
  const int idx = blockIdx.x * 256 + threadIdx.x;
  if (idx >= 1568 * 192) return;
  const int d = idx % 192;
  const int r2 = idx / 192;
  const int b = r2 / 784, l2 = r2 % 784;
  const int h2 = l2 / 28, w2 = l2 % 28;
  const float* p = v + (size_t)(b * 3136 + h2 * 2 * 56 + w2 * 2) * 192 + d;
  vp[idx] = fmaxf(fmaxf(p[0], p[192]), fmaxf(p[56 * 192], p[57 * 192]));
}

// ---------------- scan phase 1: per-chunk (prod dA, local state) ----------------
__global__ __launch_bounds__(256) void k_scan1(
    const float* __restrict__ dt, const float* __restrict__ xi,
    const float* __restrict__ bc, const float* __restrict__ A_log,
    float* __restrict__ P, float* __restrict__ S, int Lseq, int NC)
{
  constexpr int LC = 112, ST = 116;
  __shared__ float dts[16 * ST], xis[16 * ST], bms[16 * ST];
  const int tid = threadIdx.x;
  const int eg = blockIdx.x % 24;
  const int c = (blockIdx.x / 24) % NC;
  const int b = blockIdx.x / (24 * NC);
  const int rowbase = b * Lseq + c * LC;
  for (int idx = tid; idx < LC * 4; idx += 256) {
    const int l = idx >> 2, q = idx & 3;
    float4 t = *(const float4*)(dt + (size_t)(rowbase + l) * 384 + eg * 16 + q * 4);
    dts[(q * 4 + 0) * ST + l] = t.x; dts[(q * 4 + 1) * ST + l] = t.y;
    dts[(q * 4 + 2) * ST + l] = t.z; dts[(q * 4 + 3) * ST + l] = t.w;
    t = *(const float4*)(xi + (size_t)(rowbase + l) * 384 + eg * 16 + q * 4);
    xis[(q * 4 + 0) * ST + l] = t.x; xis[(q * 4 + 1) * ST + l] = t.y;
    xis[(q * 4 + 2) * ST + l] = t.z; xis[(q * 4 + 3) * ST + l] = t.w;
    t = *(const float4*)(bc + (size_t)(rowbase + l) * 32 + q * 4);
    bms[(q * 4 + 0) * ST + l] = t.x; bms[(q * 4 + 1) * ST + l] = t.y;
    bms[(q * 4 + 2) * ST + l] = t.z; bms[(q * 4 + 3) * ST + l] = t.w;
  }
  __syncthreads();
  const int n = tid & 15, eo = tid >> 4;
  const int e = eg * 16 + eo;
  const float An2 = -__expf(A_log[e * 16 + n]) * 1.44269504f;
  float h = 0.f, ap = 1.f;
#pragma unroll 4
  for (int l = 0; l < LC; ++l) {
    const float dtv = dts[eo * ST + l];
    const float u = dtv * xis[eo * ST + l];
    const float a = __builtin_amdgcn_exp2f(dtv * An2);
    h = a * h + u * bms[n * ST + l];
    ap *= a;
  }
  const size_t o = ((size_t)(b * NC + c) * 384 + e) * 16 + n;
  P[o] = ap; S[o] = h;
}

// ---------------- scan phase 2: fold carry, recompute, emit y ----------------
__global__ __launch_bounds__(256) void k_scan2(
    const float* __restrict__ dt, const float* __restrict__ xi,
    const float* __restrict__ bc, const float* __restrict__ xz,
    const float* __restrict__ A_log, const float* __restrict__ Dskip,
    const float* __restrict__ P, const float* __restrict__ S,
    float* __restrict__ y, int Lseq, int NC)
{
  constexpr int LC = 112, ST = 116;
  __shared__ float dts[16 * ST], xis[16 * ST], bms[16 * ST], cms[16 * ST], zs[16 * ST], ys[16 * ST];
  const int tid = threadIdx.x;
  const int eg = blockIdx.x % 24;
  const int c = (blockIdx.x / 24) % NC;
  const int b = blockIdx.x / (24 * NC);
  const int rowbase = b * Lseq + c * LC;
  for (int idx = tid; idx < LC * 4; idx += 256) {
    const int l = idx >> 2, q = idx & 3;
    float4 t = *(const float4*)(dt + (size_t)(rowbase + l) * 384 + eg * 16 + q * 4);
    dts[(q * 4 + 0) * ST + l] = t.x; dts[(q * 4 + 1) * ST + l] = t.y;
    dts[(q * 4 + 2) * ST + l] = t.z; dts[(q * 4 + 3) * ST + l] = t.w;
    t = *(const float4*)(xi + (size_t)(rowbase + l) * 384 + eg * 16 + q * 4);
    xis[(q * 4 + 0) * ST + l] = t.x; xis[(q * 4 + 1) * ST + l] = t.y;
    xis[(q * 4 + 2) * ST + l] = t.z; xis[(q * 4 + 3) * ST + l] = t.w;
    t = *(const float4*)(bc + (size_t)(rowbase + l) * 32 + q * 4);
    bms[(q * 4 + 0) * ST + l] = t.x; bms[(q * 4 + 1) * ST + l] = t.y;
    bms[(q * 4 + 2) * ST + l] = t.z; bms[(q * 4 + 3) * ST + l] = t.w;
    t = *(const float4*)(bc + (size_t)(rowbase + l) * 32 + 16 + q * 4);
    cms[(q * 4 + 0) * ST + l] = t.x; cms[(q * 4 + 1) * ST + l] = t.y;
    cms[(q * 4 + 2) * ST + l] = t.z; cms[(q * 4 + 3) * ST + l] = t.w;
    t = *(const float4*)(xz + (size_t)(rowbase + l) * 768 + 384 + eg * 16 + q * 4);
    zs[(q * 4 + 0) * ST + l] = t.x; zs[(q * 4 + 1) * ST + l] = t.y;
    zs[(q * 4 + 2) * ST + l] = t.z; zs[(q * 4 + 3) * ST + l] = t.w;
  }
  __syncthreads();
  const int n = tid & 15, eo = tid >> 4;
  const int e = eg * 16 + eo;
  const float An2 = -__expf(A_log[e * 16 + n]) * 1.44269504f;
  float h = 0.f;
  for (int c2 = 0; c2 < c; ++c2) {
    const size_t o = ((size_t)(b * NC + c2) * 384 + e) * 16 + n;
    h = P[o] * h + S[o];
  }
  const float Dse = Dskip[e];
  for (int l = 0; l < LC; ++l) {
    const float dtv = dts[eo * ST + l];
    const float xiv = xis[eo * ST + l];
    const float a = __builtin_amdgcn_exp2f(dtv * An2);
    h = a * h + dtv * xiv * bms[n * ST + l];
    float p = h * cms[n * ST + l];
    p += __shfl_xor(p, 1); p += __shfl_xor(p, 2);
    p += __shfl_xor(p, 4); p += __shfl_xor(p, 8);
    if (n == 0) ys[eo * ST + l] = (p + Dse * xiv) * siluf(zs[eo * ST + l]);
  }
  __syncthreads();
  for (int idx = tid; idx < LC * 4; idx += 256) {
    const int l = idx >> 2, q = idx & 3;
    float4 t;
    t.x = ys[(q * 4 + 0) * ST + l]; t.y = ys[(q * 4 + 1) * ST + l];
    t.z = ys[(q * 4 + 2) * ST + l]; t.w = ys[(q * 4 + 3) * ST + l];
    *(float4*)(y + (size_t)(rowbase + l) * 384 + eg * 16 + q * 4) = t;
  }
}

extern "C" void kernel_launch(void* const* d_in, const int* in_sizes, int n_in,
                              void* d_out, int out_size, void* d_ws, size_t ws_size,
                              hipStream_t stream)
{
  const float* x    = (const float*)d_in[0];
  const float* pw   = (const float*)d_in[1];
  const float* pb   = (const float*)d_in[2];
  const float* bng  = (const float*)d_in[3];
  const float* bnb  = (const float*)d_in[4];
  const float* bnm  = (const float*)d_in[5];
  const float* bnv  = (const float*)d_in[6];
  const float* lng  = (const float*)d_in[7];
  const float* lnb  = (const float*)d_in[8];
  const float* Win  = (const float*)d_in[9];
  const float* b_in = (const float*)d_in[10];
  const float* cw   = (const float*)d_in[11];
  const float* cb   = (const float*)d_in[12];
  const float* Wx   = (const float*)d_in[13];
  const float* Wdt  = (const float*)d_in[14];
  const float* bdt  = (const float*)d_in[15];
  const float* Alog = (const float*)d_in[16];
  const float* Dsk  = (const float*)d_in[17];
  const float* Wout = (const float*)d_in[18];
  const float* bout = (const float*)d_in[19];

  float* wsf = (float*)d_ws;
  float* v   = wsf;                  // 1204224
  float* xz  = v + 1204224;          // 4816896
  float* xib = xz + 4816896;         // 2408448
  float* dtb = xib + 2408448;        // 2408448
  float* bcb = dtb + 2408448;        // 200704
  float* yb  = bcb + 200704;         // 2408448
  float* vp  = yb + 2408448;         // 301056
  float* Pb  = vp + 301056;          // 344064
  float* Sb  = Pb + 344064;          // 344064

  float* out0 = (float*)d_out;
  float* out1 = out0 + 301056;

  k_proj_bn<<<196, 192, 0, stream>>>(x, pw, pb, bng, bnb, bnm, bnv, v);

  for (int i = 0; i < 3; ++i) {
    const int big = (i < 2) ? 1 : 0;
    const int Lseq = big ? 3136 : 784;
    const int M = 2 * Lseq;
    const int NC = big ? 28 : 7;
    const int MB = (M + 63) / 64;
    const float* lng_i = lng + i * 192;
    const float* lnb_i = lnb + i * 192;
    const float* Win_i = Win + i * 768 * 192;
    const float* bin_i = b_in + i * 768;
    const float* cw_i  = cw + i * 384 * 4;
    const float* cb_i  = cb + i * 384;
    const float* Wx_i  = Wx + i * 44 * 384;
    const float* Wdt_i = Wdt + i * 384 * 12;
    const float* bdt_i = bdt + i * 384;
    const float* Al_i  = Alog + i * 384 * 16;
    const float* Ds_i  = Dsk + i * 384;
    const float* Wo_i  = Wout + i * 192 * 384;
    const float* bo_i  = bout + i * 192;

    if (i == 2)
      k_pool<<<(1568 * 192 + 255) / 256, 256, 0, stream>>>(v, vp);
    const float* src = big ? v : vp;

    k_gemm<1, EPI_XZ><<<dim3(MB, 12), 256, 0, stream>>>(
        src, Win_i, bin_i, xz, M, 192, 768, lng_i, lnb_i,
        nullptr, nullptr, nullptr, nullptr, nullptr, Lseq);
    k_conv<<<(M * 384 + 255) / 256, 256, 0, stream>>>(xz, xib, cw_i, cb_i, Lseq, M * 384);
    k_gemm<0, EPI_G2><<<dim3(MB, 1), 256, 0, stream>>>(
        xib, Wx_i, nullptr, nullptr, M, 384, 44, nullptr, nullptr,
        Wdt_i, bdt_i, dtb, bcb, nullptr, Lseq);
    k_scan1<<<2 * NC * 24, 256, 0, stream>>>(dtb, xib, bcb, Al_i, Pb, Sb, Lseq, NC);
    k_scan2<<<2 * NC * 24, 256, 0, stream>>>(dtb, xib, bcb, xz, Al_i, Ds_i, Pb, Sb, yb, Lseq, NC);
    if (i == 0)
      k_gemm<0, EPI_RES><<<dim3(MB, 3), 256, 0, stream>>>(
          yb, Wo_i, bo_i, v, M, 384, 192, nullptr, nullptr,
          nullptr, nullptr, nullptr, nullptr, nullptr, Lseq);
    else if (i == 1)
      k_gemm<0, EPI_RES_SKIP><<<dim3(MB, 3), 256, 0, stream>>>(
          yb, Wo_i, bo_i, v, M, 384, 192, nullptr, nullptr,
          nullptr, nullptr, nullptr, nullptr, out1, Lseq);
    else
      k_gemm<0, EPI_OUT2><<<dim3(MB, 3), 256, 0, stream>>>(
          yb, Wo_i, bo_i, nullptr, M, 384, 192, nullptr, nullptr,
          nullptr, nullptr, nullptr, nullptr, out0, Lseq);
  }
}

// Round 4
// 598.648 us; speedup vs baseline: 1.0157x; 1.0157x over previous
//
#include <hip/hip_runtime.h>

typedef __attribute__((ext_vector_type(8))) __bf16 bf16x8;
typedef __attribute__((ext_vector_type(4))) __bf16 bf16x4;
typedef __attribute__((ext_vector_type(4))) float f32x4;

#define DEV static __device__ __forceinline__

DEV float fast_rcp(float x) { return __builtin_amdgcn_rcpf(x); }
DEV float sigm(float x) { return fast_rcp(1.f + __expf(-x)); }
DEV float siluf(float x) { return x * sigm(x); }
DEV float softplusf(float x) { return x > 20.f ? x : __logf(1.f + __expf(x)); }

// ---------------- K0: 1x1 conv projection (96->192) + BN, write v (BL,192) fp32 ----
__global__ __launch_bounds__(192) void k_proj_bn(
    const float* __restrict__ x, const float* __restrict__ pw,
    const float* __restrict__ pb, const float* __restrict__ bng,
    const float* __restrict__ bnb, const float* __restrict__ bnm,
    const float* __restrict__ bnv, float* __restrict__ v)
{
  __shared__ float pwT[96 * 192];
  __shared__ float sc[192], sh[192];
  __shared__ float xs[96];
  const int tid = threadIdx.x;
  for (int idx = tid; idx < 96 * 192; idx += 192) {
    int o = idx / 96, c = idx % 96;
    pwT[c * 192 + o] = pw[idx];
  }
  {
    float rstd = rsqrtf(bnv[tid] + 1e-5f);
    float s = rstd * bng[tid];
    sc[tid] = s;
    sh[tid] = (pb[tid] - bnm[tid]) * s + bnb[tid];
  }
  const int p0 = blockIdx.x * 32;
  for (int p = 0; p < 32; ++p) {
    const int pix = p0 + p;
    const int b = pix / 3136, l = pix % 3136;
    __syncthreads();
    if (tid < 96) xs[tid] = x[(b * 96 + tid) * 3136 + l];
    __syncthreads();
    float acc = 0.f;
#pragma unroll 8
    for (int c = 0; c < 96; ++c) acc += xs[c] * pwT[c * 192 + tid];
    v[pix * 192 + tid] = acc * sc[tid] + sh[tid];
  }
}

// ---------------- generic MFMA GEMM: O[r,e] = sum_d A[r,d]*W[e,d] ----------------
constexpr int EPI_XZ = 0, EPI_G2 = 1, EPI_RES = 2, EPI_RES_SKIP = 3, EPI_OUT2 = 4;

template <int LNMODE, int EPI>
__global__ __launch_bounds__(256) void k_gemm(
    const float* __restrict__ A, const float* __restrict__ W,
    const float* __restrict__ bias, float* __restrict__ O,
    int M, int K, int Nvalid,
    const float* __restrict__ lng, const float* __restrict__ lnb,
    const float* __restrict__ Wdt, const float* __restrict__ bdt,
    float* __restrict__ dtbuf, float* __restrict__ bcbuf,
    float* __restrict__ oflt, int Lseq)
{
  constexpr int SA = 200;  // LDS row stride in bf16 (192+8)
  __shared__ __bf16 As[64 * SA];
  __shared__ __bf16 Ws[64 * SA];
  __shared__ float lngS[192], lnbS[192];
  const int tid = threadIdx.x;
  const int r0 = blockIdx.x * 64;
  const int col0 = blockIdx.y * 64;
  const int lane = tid & 63, wv = tid >> 6;
  const int rh = wv >> 1, ch = wv & 1;
  const int lm = lane & 15, quad = lane >> 4;

  if constexpr (LNMODE == 1) {
    if (tid < 192) { lngS[tid] = lng[tid]; lnbS[tid] = lnb[tid]; }
    __syncthreads();
  }

  f32x4 acc[2][2] = {};
  const int nkp = K / 192;
  for (int kp = 0; kp < nkp; ++kp) {
    if (kp) __syncthreads();
    // ---- stage A (fp32 -> bf16, optional LN) ----
    {
      const int row = tid >> 2, part = tid & 3;
      const int grow = r0 + row;
      const int cbase = part * 48;
      float4 tv[12];
      if (grow < M) {
#pragma unroll
        for (int j = 0; j < 12; ++j)
          tv[j] = *(const float4*)(A + (size_t)grow * K + kp * 192 + cbase + j * 4);
      } else {
#pragma unroll
        for (int j = 0; j < 12; ++j) tv[j] = make_float4(0.f, 0.f, 0.f, 0.f);
      }
      if constexpr (LNMODE == 1) {
        float s = 0.f, sq = 0.f;
#pragma unroll
        for (int j = 0; j < 12; ++j) {
          s += tv[j].x + tv[j].y + tv[j].z + tv[j].w;
          sq += tv[j].x * tv[j].x + tv[j].y * tv[j].y + tv[j].z * tv[j].z + tv[j].w * tv[j].w;
        }
        s += __shfl_xor(s, 1); s += __shfl_xor(s, 2);
        sq += __shfl_xor(sq, 1); sq += __shfl_xor(sq, 2);
        const float mean = s * (1.f / 192.f);
        const float rstd = rsqrtf(sq * (1.f / 192.f) - mean * mean + 1e-5f);
#pragma unroll
        for (int j = 0; j < 12; ++j) {
          const int c = cbase + j * 4;
          tv[j].x = (tv[j].x - mean) * rstd * lngS[c + 0] + lnbS[c + 0];
          tv[j].y = (tv[j].y - mean) * rstd * lngS[c + 1] + lnbS[c + 1];
          tv[j].z = (tv[j].z - mean) * rstd * lngS[c + 2] + lnbS[c + 2];
          tv[j].w = (tv[j].w - mean) * rstd * lngS[c + 3] + lnbS[c + 3];
        }
      }
#pragma unroll
      for (int j = 0; j < 12; ++j) {
        bf16x4 o;
        o[0] = (__bf16)tv[j].x; o[1] = (__bf16)tv[j].y;
        o[2] = (__bf16)tv[j].z; o[3] = (__bf16)tv[j].w;
        *(bf16x4*)(&As[row * SA + cbase + j * 4]) = o;
      }
    }
    // ---- stage W (fp32 global row-major (N,K) -> bf16 LDS) ----
#pragma unroll
    for (int it = 0; it < 12; ++it) {
      const int idx = tid + it * 256;          // 0..3071
      const int wr = idx / 48, c4 = (idx % 48) * 4;
      const int gw = col0 + wr;
      float4 t = make_float4(0.f, 0.f, 0.f, 0.f);
      if (gw < Nvalid) t = *(const float4*)(W + (size_t)gw * K + kp * 192 + c4);
      bf16x4 o;
      o[0] = (__bf16)t.x; o[1] = (__bf16)t.y; o[2] = (__bf16)t.z; o[3] = (__bf16)t.w;
      *(bf16x4*)(&Ws[wr * SA + c4]) = o;
    }
    __syncthreads();
    // ---- mfma 6 k-steps ----
#pragma unroll
    for (int ks = 0; ks < 6; ++ks) {
      const int kb = ks * 32 + quad * 8;
      bf16x8 a0 = *(const bf16x8*)(&As[(rh * 32 + lm) * SA + kb]);
      bf16x8 a1 = *(const bf16x8*)(&As[(rh * 32 + 16 + lm) * SA + kb]);
      bf16x8 b0 = *(const bf16x8*)(&Ws[(ch * 32 + lm) * SA + kb]);
      bf16x8 b1 = *(const bf16x8*)(&Ws[(ch * 32 + 16 + lm) * SA + kb]);
      acc[0][0] = __builtin_amdgcn_mfma_f32_16x16x32_bf16(a0, b0, acc[0][0], 0, 0, 0);
      acc[0][1] = __builtin_amdgcn_mfma_f32_16x16x32_bf16(a0, b1, acc[0][1], 0, 0, 0);
      acc[1][0] = __builtin_amdgcn_mfma_f32_16x16x32_bf16(a1, b0, acc[1][0], 0, 0, 0);
      acc[1][1] = __builtin_amdgcn_mfma_f32_16x16x32_bf16(a1, b1, acc[1][1], 0, 0, 0);
    }
  }

  // ---- epilogue ----
  if constexpr (EPI == EPI_G2) {
    __shared__ float dtlS[64 * 12];
    __shared__ float wdtS[12 * 384];
#pragma unroll
    for (int ti = 0; ti < 2; ++ti)
#pragma unroll
      for (int tj = 0; tj < 2; ++tj) {
        const int colt = ch * 32 + tj * 16 + lm;
#pragma unroll
        for (int j = 0; j < 4; ++j) {
          const int rowt = rh * 32 + ti * 16 + quad * 4 + j;
          const int grow = r0 + rowt;
          const float val = acc[ti][tj][j];
          if (colt < 12) dtlS[rowt * 12 + colt] = val;            // dtl
          else if (colt < 44 && grow < M)
            bcbuf[(size_t)grow * 32 + (colt - 12)] = val;         // Bm(0..15), Cm(16..31)
        }
      }
    for (int idx = tid; idx < 12 * 384; idx += 256) {
      const int e = idx / 12, r = idx % 12;
      wdtS[r * 384 + e] = Wdt[idx];
    }
    __syncthreads();
    for (int it = 0; it < 96; ++it) {
      const int flat = tid + it * 256;
      const int rr = flat / 384, e = flat % 384;
      const int grow = r0 + rr;
      if (grow < M) {
        float a = bdt[e];
#pragma unroll
        for (int r = 0; r < 12; ++r) a += dtlS[rr * 12 + r] * wdtS[r * 384 + e];
        dtbuf[(size_t)grow * 384 + e] = softplusf(a);
      }
    }
  } else {
#pragma unroll
    for (int ti = 0; ti < 2; ++ti)
#pragma unroll
      for (int tj = 0; tj < 2; ++tj) {
        const int colt = ch * 32 + tj * 16 + lm;
        const int gcol = col0 + colt;
        const float bv = bias[gcol];
#pragma unroll
        for (int j = 0; j < 4; ++j) {
          const int rowt = rh * 32 + ti * 16 + quad * 4 + j;
          const int grow = r0 + rowt;
          if (grow >= M) continue;
          const float val = acc[ti][tj][j] + bv;
          if constexpr (EPI == EPI_XZ) {
            O[(size_t)grow * 768 + gcol] = val;
          } else if constexpr (EPI == EPI_RES) {
            O[(size_t)grow * 192 + gcol] += val;
          } else if constexpr (EPI == EPI_RES_SKIP) {
            const float nv = O[(size_t)grow * 192 + gcol] + val;
            O[(size_t)grow * 192 + gcol] = nv;
            const int b = grow / 3136, l = grow % 3136;
            oflt[b * 602112 + gcol * 3136 + l] = nv;              // skip (B,192,56,56) fp32
          } else {  // EPI_OUT2
            const int b = grow / 784, l = grow % 784;
            oflt[b * 150528 + gcol * 784 + l] = val;              // out0 (B,192,28,28) fp32
          }
        }
      }
  }
}

// ---------------- depthwise causal conv K=4 + silu ----------------
__global__ __launch_bounds__(256) void k_conv(
    const float* __restrict__ xz, float* __restrict__ xi,
    const float* __restrict__ cw, const float* __restrict__ cb,
    int Lseq, int total)
{
  const int idx = blockIdx.x * 256 + threadIdx.x;
  if (idx >= total) return;
  const int e = idx % 384;
  const int row = idx / 384;
  const int l = row % Lseq;
  const float4 w4 = *(const float4*)(cw + e * 4);
  float acc = cb[e];
  if (l >= 3) acc += xz[(size_t)(row - 3) * 768 + e] * w4.x;
  if (l >= 2) acc += xz[(size_t)(row - 2) * 768 + e] * w4.y;
  if (l >= 1) acc += xz[(size_t)(row - 1) * 768 + e] * w4.z;
  acc += xz[(size_t)row * 768 + e] * w4.w;
  xi[idx] = siluf(acc);
}

// ---------------- 2x2 maxpool ----------------
__global__ __launch_bounds__(256) void k_pool(const float* __restrict__ v, float* __restrict__ vp)
{
  const int idx = blockIdx.x * 256 + threadIdx.x;
  if (idx >= 1568 * 192) return;
  const int d = idx % 192;
  const int r2 = idx / 192;
  const int b = r2 / 784, l2 = r2 % 784;
  const int h2 = l2 / 28, w2 = l2 % 28;
  const float* p = v + (size_t)(b * 3136 + h2 * 2 * 56 + w2 * 2) * 192 + d;
  vp[idx] = fmaxf(fmaxf(p[0], p[192]), fmaxf(p[56 * 192], p[57 * 192]));
}

// ======== chunked selective scan, register-state layout: 1 thread = 1 channel e ========
// LC=56 steps/chunk. Grid: (2*NC, 3) blocks of 128 threads; e = blockIdx.y*128+tid.
constexpr int SC_LC = 56, SC_T = 8, SC_TN = 7;

// phase 1: per-chunk (prod dA)[16], local end-state[16] per channel
__global__ __launch_bounds__(128) void k_scan1(
    const float* __restrict__ dt, const float* __restrict__ xi,
    const float* __restrict__ bc, const float* __restrict__ A_log,
    float* __restrict__ P, float* __restrict__ S, int Lseq, int NC)
{
  const int e = blockIdx.y * 128 + threadIdx.x;
  const int c = blockIdx.x % NC;
  const int b = blockIdx.x / NC;
  const int rowbase = b * Lseq + c * SC_LC;

  float An2[16];
  {
    const float4* a4 = (const float4*)(A_log + e * 16);
    float4 t0 = a4[0], t1 = a4[1], t2 = a4[2], t3 = a4[3];
    float tmp[16] = {t0.x, t0.y, t0.z, t0.w, t1.x, t1.y, t1.z, t1.w,
                     t2.x, t2.y, t2.z, t2.w, t3.x, t3.y, t3.z, t3.w};
#pragma unroll
    for (int n = 0; n < 16; ++n) An2[n] = -__expf(tmp[n]) * 1.44269504f;
  }
  float h[16], ap[16];
#pragma unroll
  for (int n = 0; n < 16; ++n) { h[n] = 0.f; ap[n] = 1.f; }

  float dA[SC_T], xA[SC_T], dB[SC_T], xB[SC_T];
  auto LOADA = [&](int t) {
#pragma unroll
    for (int j = 0; j < SC_T; ++j) {
      const size_t r = (size_t)(rowbase + t * SC_T + j) * 384 + e;
      dA[j] = dt[r]; xA[j] = xi[r];
    }
  };
  auto LOADB = [&](int t) {
#pragma unroll
    for (int j = 0; j < SC_T; ++j) {
      const size_t r = (size_t)(rowbase + t * SC_T + j) * 384 + e;
      dB[j] = dt[r]; xB[j] = xi[r];
    }
  };
  auto COMP = [&](const float (&d8)[SC_T], const float (&x8)[SC_T], int t) {
#pragma unroll
    for (int j = 0; j < SC_T; ++j) {
      const int l = t * SC_T + j;
      const float dtv = d8[j];
      const float u = dtv * x8[j];
      const float4* br = (const float4*)(bc + (size_t)(rowbase + l) * 32);
      const float4 B0 = br[0], B1 = br[1], B2 = br[2], B3 = br[3];
      const float Bv[16] = {B0.x, B0.y, B0.z, B0.w, B1.x, B1.y, B1.z, B1.w,
                            B2.x, B2.y, B2.z, B2.w, B3.x, B3.y, B3.z, B3.w};
#pragma unroll
      for (int n = 0; n < 16; ++n) {
        const float a = __builtin_amdgcn_exp2f(dtv * An2[n]);
        h[n] = a * h[n] + u * Bv[n];
        ap[n] *= a;
      }
    }
  };

  LOADA(0);
#pragma unroll
  for (int t = 0; t < SC_TN; ++t) {
    if (t & 1) { if (t + 1 < SC_TN) LOADA(t + 1); COMP(dB, xB, t); }
    else       { if (t + 1 < SC_TN) LOADB(t + 1); COMP(dA, xA, t); }
  }

  const size_t o = ((size_t)(b * NC + c) * 384 + e) * 16;
#pragma unroll
  for (int q = 0; q < 4; ++q) {
    *(float4*)(P + o + q * 4) = make_float4(ap[q*4], ap[q*4+1], ap[q*4+2], ap[q*4+3]);
    *(float4*)(S + o + q * 4) = make_float4(h[q*4], h[q*4+1], h[q*4+2], h[q*4+3]);
  }
}

// carry: prefix-fold chunk (P,S) -> H0 (in-place over S; read-before-write per element)
__global__ __launch_bounds__(256) void k_carry(
    const float* __restrict__ P, float* __restrict__ SH, int NC)
{
  const int tid = blockIdx.x * 256 + threadIdx.x;   // 12288 total
  const int b = tid / 6144, r = tid % 6144;
  float h = 0.f;
  for (int c = 0; c < NC; ++c) {
    const size_t o = ((size_t)b * NC + c) * 6144 + r;
    const float p = P[o], s = SH[o];
    SH[o] = h;
    h = p * h + s;
  }
}

// phase 2: init from H0, recompute chunk, emit gated y
__global__ __launch_bounds__(128) void k_scan2(
    const float* __restrict__ dt, const float* __restrict__ xi,
    const float* __restrict__ bc, const float* __restrict__ xz,
    const float* __restrict__ A_log, const float* __restrict__ Dskip,
    const float* __restrict__ H0, float* __restrict__ y, int Lseq, int NC)
{
  const int e = blockIdx.y * 128 + threadIdx.x;
  const int c = blockIdx.x % NC;
  const int b = blockIdx.x / NC;
  const int rowbase = b * Lseq + c * SC_LC;

  float An2[16];
  {
    const float4* a4 = (const float4*)(A_log + e * 16);
    float4 t0 = a4[0], t1 = a4[1], t2 = a4[2], t3 = a4[3];
    float tmp[16] = {t0.x, t0.y, t0.z, t0.w, t1.x, t1.y, t1.z, t1.w,
                     t2.x, t2.y, t2.z, t2.w, t3.x, t3.y, t3.z, t3.w};
#pragma unroll
    for (int n = 0; n < 16; ++n) An2[n] = -__expf(tmp[n]) * 1.44269504f;
  }
  float h[16];
  {
    const size_t o = ((size_t)(b * NC + c) * 384 + e) * 16;
    const float4* h4 = (const float4*)(H0 + o);
    float4 t0 = h4[0], t1 = h4[1], t2 = h4[2], t3 = h4[3];
    h[0]=t0.x; h[1]=t0.y; h[2]=t0.z; h[3]=t0.w;
    h[4]=t1.x; h[5]=t1.y; h[6]=t1.z; h[7]=t1.w;
    h[8]=t2.x; h[9]=t2.y; h[10]=t2.z; h[11]=t2.w;
    h[12]=t3.x; h[13]=t3.y; h[14]=t3.z; h[15]=t3.w;
  }
  const float Dse = Dskip[e];

  float dA[SC_T], xA[SC_T], zA[SC_T], dB[SC_T], xB[SC_T], zB[SC_T];
  auto LOADA = [&](int t) {
#pragma unroll
    for (int j = 0; j < SC_T; ++j) {
      const size_t r = (size_t)(rowbase + t * SC_T + j);
      dA[j] = dt[r * 384 + e]; xA[j] = xi[r * 384 + e];
      zA[j] = xz[r * 768 + 384 + e];
    }
  };
  auto LOADB = [&](int t) {
#pragma unroll
    for (int j = 0; j < SC_T; ++j) {
      const size_t r = (size_t)(rowbase + t * SC_T + j);
      dB[j] = dt[r * 384 + e]; xB[j] = xi[r * 384 + e];
      zB[j] = xz[r * 768 + 384 + e];
    }
  };
  auto COMP = [&](const float (&d8)[SC_T], const float (&x8)[SC_T],
                  const float (&z8)[SC_T], int t) {
#pragma unroll
    for (int j = 0; j < SC_T; ++j) {
      const int l = t * SC_T + j;
      const float dtv = d8[j];
      const float xiv = x8[j];
      const float u = dtv * xiv;
      const float4* br = (const float4*)(bc + (size_t)(rowbase + l) * 32);
      const float4 B0 = br[0], B1 = br[1], B2 = br[2], B3 = br[3];
      const float4 C0 = br[4], C1 = br[5], C2 = br[6], C3 = br[7];
      const float Bv[16] = {B0.x, B0.y, B0.z, B0.w, B1.x, B1.y, B1.z, B1.w,
                            B2.x, B2.y, B2.z, B2.w, B3.x, B3.y, B3.z, B3.w};
      const float Cv[16] = {C0.x, C0.y, C0.z, C0.w, C1.x, C1.y, C1.z, C1.w,
                            C2.x, C2.y, C2.z, C2.w, C3.x, C3.y, C3.z, C3.w};
      float yv = 0.f;
#pragma unroll
      for (int n = 0; n < 16; ++n) {
        const float a = __builtin_amdgcn_exp2f(dtv * An2[n]);
        h[n] = a * h[n] + u * Bv[n];
        yv += h[n] * Cv[n];
      }
      y[(size_t)(rowbase + l) * 384 + e] = (yv + Dse * xiv) * siluf(z8[j]);
    }
  };

  LOADA(0);
#pragma unroll
  for (int t = 0; t < SC_TN; ++t) {
    if (t & 1) { if (t + 1 < SC_TN) LOADA(t + 1); COMP(dB, xB, zB, t); }
    else       { if (t + 1 < SC_TN) LOADB(t + 1); COMP(dA, xA, zA, t); }
  }
}

extern "C" void kernel_launch(void* const* d_in, const int* in_sizes, int n_in,
                              void* d_out, int out_size, void* d_ws, size_t ws_size,
                              hipStream_t stream)
{
  const float* x    = (const float*)d_in[0];
  const float* pw   = (const float*)d_in[1];
  const float* pb   = (const float*)d_in[2];
  const float* bng  = (const float*)d_in[3];
  const float* bnb  = (const float*)d_in[4];
  const float* bnm  = (const float*)d_in[5];
  const float* bnv  = (const float*)d_in[6];
  const float* lng  = (const float*)d_in[7];
  const float* lnb  = (const float*)d_in[8];
  const float* Win  = (const float*)d_in[9];
  const float* b_in = (const float*)d_in[10];
  const float* cw   = (const float*)d_in[11];
  const float* cb   = (const float*)d_in[12];
  const float* Wx   = (const float*)d_in[13];
  const float* Wdt  = (const float*)d_in[14];
  const float* bdt  = (const float*)d_in[15];
  const float* Alog = (const float*)d_in[16];
  const float* Dsk  = (const float*)d_in[17];
  const float* Wout = (const float*)d_in[18];
  const float* bout = (const float*)d_in[19];

  float* wsf = (float*)d_ws;
  float* v   = wsf;                  // 1204224
  float* xz  = v + 1204224;          // 4816896
  float* xib = xz + 4816896;         // 2408448
  float* dtb = xib + 2408448;        // 2408448
  float* bcb = dtb + 2408448;        // 200704
  float* yb  = bcb + 200704;         // 2408448 (P overlays this: lifetimes disjoint)
  float* vp  = yb + 2408448;         // 301056
  float* Sb  = vp + 301056;          // 688128 (S, then H0 in-place)
  float* Pb  = yb;                   // alias: scan1-write/carry-read before scan2 writes y

  float* out0 = (float*)d_out;
  float* out1 = out0 + 301056;

  k_proj_bn<<<196, 192, 0, stream>>>(x, pw, pb, bng, bnb, bnm, bnv, v);

  for (int i = 0; i < 3; ++i) {
    const int big = (i < 2) ? 1 : 0;
    const int Lseq = big ? 3136 : 784;
    const int M = 2 * Lseq;
    const int NC = Lseq / SC_LC;     // 56 big, 14 small
    const int MB = (M + 63) / 64;
    const float* lng_i = lng + i * 192;
    const float* lnb_i = lnb + i * 192;
    const float* Win_i = Win + i * 768 * 192;
    const float* bin_i = b_in + i * 768;
    const float* cw_i  = cw + i * 384 * 4;
    const float* cb_i  = cb + i * 384;
    const float* Wx_i  = Wx + i * 44 * 384;
    const float* Wdt_i = Wdt + i * 384 * 12;
    const float* bdt_i = bdt + i * 384;
    const float* Al_i  = Alog + i * 384 * 16;
    const float* Ds_i  = Dsk + i * 384;
    const float* Wo_i  = Wout + i * 192 * 384;
    const float* bo_i  = bout + i * 192;

    if (i == 2)
      k_pool<<<(1568 * 192 + 255) / 256, 256, 0, stream>>>(v, vp);
    const float* src = big ? v : vp;

    k_gemm<1, EPI_XZ><<<dim3(MB, 12), 256, 0, stream>>>(
        src, Win_i, bin_i, xz, M, 192, 768, lng_i, lnb_i,
        nullptr, nullptr, nullptr, nullptr, nullptr, Lseq);
    k_conv<<<(M * 384 + 255) / 256, 256, 0, stream>>>(xz, xib, cw_i, cb_i, Lseq, M * 384);
    k_gemm<0, EPI_G2><<<dim3(MB, 1), 256, 0, stream>>>(
        xib, Wx_i, nullptr, nullptr, M, 384, 44, nullptr, nullptr,
        Wdt_i, bdt_i, dtb, bcb, nullptr, Lseq);
    k_scan1<<<dim3(2 * NC, 3), 128, 0, stream>>>(dtb, xib, bcb, Al_i, Pb, Sb, Lseq, NC);
    k_carry<<<48, 256, 0, stream>>>(Pb, Sb, NC);
    k_scan2<<<dim3(2 * NC, 3), 128, 0, stream>>>(dtb, xib, bcb, xz, Al_i, Ds_i, Sb, yb, Lseq, NC);
    if (i == 0)
      k_gemm<0, EPI_RES><<<dim3(MB, 3), 256, 0, stream>>>(
          yb, Wo_i, bo_i, v, M, 384, 192, nullptr, nullptr,
          nullptr, nullptr, nullptr, nullptr, nullptr, Lseq);
    else if (i == 1)
      k_gemm<0, EPI_RES_SKIP><<<dim3(MB, 3), 256, 0, stream>>>(
          yb, Wo_i, bo_i, v, M, 384, 192, nullptr, nullptr,
          nullptr, nullptr, nullptr, nullptr, out1, Lseq);
    else
      k_gemm<0, EPI_OUT2><<<dim3(MB, 3), 256, 0, stream>>>(
          yb, Wo_i, bo_i, nullptr, M, 384, 192, nullptr, nullptr,
          nullptr, nullptr, nullptr, nullptr, out0, Lseq);
  }
}

// Round 6
// 540.126 us; speedup vs baseline: 1.1257x; 1.1083x over previous
//
#include <hip/hip_runtime.h>

typedef __attribute__((ext_vector_type(8))) __bf16 bf16x8;
typedef __attribute__((ext_vector_type(4))) __bf16 bf16x4;
typedef __attribute__((ext_vector_type(4))) float f32x4;

#define DEV static __device__ __forceinline__

DEV float fast_rcp(float x) { return __builtin_amdgcn_rcpf(x); }
DEV float sigm(float x) { return fast_rcp(1.f + __expf(-x)); }
DEV float siluf(float x) { return x * sigm(x); }
DEV float softplusf(float x) { return x > 20.f ? x : __logf(1.f + __expf(x)); }

// ---------------- weight pre-convert fp32 -> bf16 (Win | Wout | Wx concatenated) ----
__global__ __launch_bounds__(256) void k_wcvt(
    const float* __restrict__ Win, const float* __restrict__ Wout,
    const float* __restrict__ Wx, __bf16* __restrict__ Wb)
{
  const int idx = blockIdx.x * 256 + threadIdx.x;
  if (idx < 442368) Wb[idx] = (__bf16)Win[idx];
  else if (idx < 663552) Wb[idx] = (__bf16)Wout[idx - 442368];
  else if (idx < 714240) Wb[idx] = (__bf16)Wx[idx - 663552];
}

// ---------------- proj (96->192) MFMA GEMM + BN, v fp32 ----------------
__global__ __launch_bounds__(256) void k_proj(
    const float* __restrict__ x, const float* __restrict__ pw,
    const float* __restrict__ pb, const float* __restrict__ bng,
    const float* __restrict__ bnb, const float* __restrict__ bnm,
    const float* __restrict__ bnv, float* __restrict__ v)
{
  constexpr int SAP = 104;
  __shared__ __bf16 As[64 * SAP];
  __shared__ __bf16 Ws[64 * SAP];
  const int tid = threadIdx.x;
  const int r0 = blockIdx.x * 64;
  const int col0 = blockIdx.y * 64;
  const int b = r0 / 3136, l0 = r0 % 3136;
  const int lane = tid & 63, wv = tid >> 6;
  const int rh = wv >> 1, ch = wv & 1;
  const int lm = lane & 15, quad = lane >> 4;

  // stage A: x channel-major, columns contiguous along l
#pragma unroll
  for (int it = 0; it < 6; ++it) {
    const int idx = tid + it * 256;       // 0..1535
    const int c = idx >> 4, l4 = idx & 15;
    const float4 t = *(const float4*)(x + ((size_t)(b * 96 + c)) * 3136 + l0 + l4 * 4);
    As[(l4 * 4 + 0) * SAP + c] = (__bf16)t.x;
    As[(l4 * 4 + 1) * SAP + c] = (__bf16)t.y;
    As[(l4 * 4 + 2) * SAP + c] = (__bf16)t.z;
    As[(l4 * 4 + 3) * SAP + c] = (__bf16)t.w;
  }
  // stage W: pw (192,96) row-major
#pragma unroll
  for (int it = 0; it < 6; ++it) {
    const int idx = tid + it * 256;
    const int wr = idx / 24, kc = (idx % 24) * 4;
    const float4 t = *(const float4*)(pw + (size_t)(col0 + wr) * 96 + kc);
    bf16x4 o;
    o[0] = (__bf16)t.x; o[1] = (__bf16)t.y; o[2] = (__bf16)t.z; o[3] = (__bf16)t.w;
    *(bf16x4*)(&Ws[wr * SAP + kc]) = o;
  }
  __syncthreads();

  f32x4 acc[2][2] = {};
#pragma unroll
  for (int ks = 0; ks < 3; ++ks) {
    const int kb = ks * 32 + quad * 8;
    bf16x8 a0 = *(const bf16x8*)(&As[(rh * 32 + lm) * SAP + kb]);
    bf16x8 a1 = *(const bf16x8*)(&As[(rh * 32 + 16 + lm) * SAP + kb]);
    bf16x8 b0 = *(const bf16x8*)(&Ws[(ch * 32 + lm) * SAP + kb]);
    bf16x8 b1 = *(const bf16x8*)(&Ws[(ch * 32 + 16 + lm) * SAP + kb]);
    acc[0][0] = __builtin_amdgcn_mfma_f32_16x16x32_bf16(a0, b0, acc[0][0], 0, 0, 0);
    acc[0][1] = __builtin_amdgcn_mfma_f32_16x16x32_bf16(a0, b1, acc[0][1], 0, 0, 0);
    acc[1][0] = __builtin_amdgcn_mfma_f32_16x16x32_bf16(a1, b0, acc[1][0], 0, 0, 0);
    acc[1][1] = __builtin_amdgcn_mfma_f32_16x16x32_bf16(a1, b1, acc[1][1], 0, 0, 0);
  }

#pragma unroll
  for (int ti = 0; ti < 2; ++ti)
#pragma unroll
    for (int tj = 0; tj < 2; ++tj) {
      const int gcol = col0 + ch * 32 + tj * 16 + lm;
      const float s = rsqrtf(bnv[gcol] + 1e-5f) * bng[gcol];
      const float sh = (pb[gcol] - bnm[gcol]) * s + bnb[gcol];
#pragma unroll
      for (int j = 0; j < 4; ++j) {
        const int grow = r0 + rh * 32 + ti * 16 + quad * 4 + j;
        v[(size_t)grow * 192 + gcol] = acc[ti][tj][j] * s + sh;
      }
    }
}

// ---------------- LN over 192 -> hb bf16 ----------------
__global__ __launch_bounds__(256) void k_ln(
    const float* __restrict__ v, const float* __restrict__ lng,
    const float* __restrict__ lnb, __bf16* __restrict__ hb)
{
  const int wv = threadIdx.x >> 6, lane = threadIdx.x & 63;
  const int row = blockIdx.x * 4 + wv;
  const float* p = v + (size_t)row * 192 + lane * 3;
  float a = p[0], b = p[1], c = p[2];
  float s = a + b + c;
  float sq = a * a + b * b + c * c;
#pragma unroll
  for (int d = 1; d < 64; d <<= 1) { s += __shfl_xor(s, d); sq += __shfl_xor(sq, d); }
  const float mean = s * (1.f / 192.f);
  const float rstd = rsqrtf(sq * (1.f / 192.f) - mean * mean + 1e-5f);
  const float* g = lng + lane * 3;
  const float* bb = lnb + lane * 3;
  __bf16* o = hb + (size_t)row * 192 + lane * 3;
  o[0] = (__bf16)((a - mean) * rstd * g[0] + bb[0]);
  o[1] = (__bf16)((b - mean) * rstd * g[1] + bb[1]);
  o[2] = (__bf16)((c - mean) * rstd * g[2] + bb[2]);
}

// ---------------- 2x2 maxpool + LN -> hb bf16 (layer 2 input) ----------------
__global__ __launch_bounds__(192) void k_pool_ln(
    const float* __restrict__ v, const float* __restrict__ lng,
    const float* __restrict__ lnb, __bf16* __restrict__ hb)
{
  __shared__ float ssum[3], ssq[3];
  const int tid = threadIdx.x;
  const int pix2 = blockIdx.x;
  const int b = pix2 / 784, l2 = pix2 % 784;
  const int h2 = l2 / 28, w2 = l2 % 28;
  const float* p = v + (size_t)(b * 3136 + h2 * 112 + w2 * 2) * 192 + tid;
  const float m = fmaxf(fmaxf(p[0], p[192]), fmaxf(p[56 * 192], p[57 * 192]));
  float s = m, sq = m * m;
#pragma unroll
  for (int d = 1; d < 64; d <<= 1) { s += __shfl_xor(s, d); sq += __shfl_xor(sq, d); }
  const int wv = tid >> 6;
  if ((tid & 63) == 0) { ssum[wv] = s; ssq[wv] = sq; }
  __syncthreads();
  const float ts = ssum[0] + ssum[1] + ssum[2];
  const float tq = ssq[0] + ssq[1] + ssq[2];
  const float mean = ts * (1.f / 192.f);
  const float rstd = rsqrtf(tq * (1.f / 192.f) - mean * mean + 1e-5f);
  hb[(size_t)pix2 * 192 + tid] = (__bf16)((m - mean) * rstd * lng[tid] + lnb[tid]);
}

// ---------------- generic MFMA GEMM: O[r,e] = sum_d A[r,d]*W[e,d] ----------------
// ABF: A is bf16 (1) or fp32 (0) in global. NT: col-tile = NT*64. W always bf16.
constexpr int EPI_XZ = 0, EPI_G2 = 1, EPI_RES = 2, EPI_RES_SKIP = 3, EPI_OUT2 = 4;

template <int ABF, int NT, int EPI>
__global__ __launch_bounds__(256) void k_gemm(
    const void* __restrict__ Ain, const __bf16* __restrict__ W,
    const float* __restrict__ bias, float* __restrict__ O,
    int M, int K, int Nvalid,
    const float* __restrict__ Wdt, const float* __restrict__ bdt,
    float* __restrict__ dtbuf, float* __restrict__ bcbuf,
    float* __restrict__ oflt)
{
  constexpr int SA = 200;
  constexpr int CT = (NT == 1) ? 2 : 4;
  __shared__ __bf16 As[64 * SA];
  __shared__ __bf16 Ws[64 * NT * SA];
  const int tid = threadIdx.x;
  const int r0 = blockIdx.x * 64;
  const int col0 = blockIdx.y * (64 * NT);
  const int lane = tid & 63, wv = tid >> 6;
  const int rh = (NT == 1) ? (wv >> 1) : (wv & 1);
  const int ch = (NT == 1) ? (wv & 1) : (wv >> 1);
  const int lm = lane & 15, quad = lane >> 4;

  f32x4 acc[2][CT] = {};
  const int nkp = K / 192;
  for (int kp = 0; kp < nkp; ++kp) {
    if (kp) __syncthreads();
    // ---- stage A ----
    if constexpr (ABF == 1) {
      const __bf16* Ab = (const __bf16*)Ain;
#pragma unroll
      for (int it = 0; it < 6; ++it) {
        const int idx = tid + it * 256;
        const int row = idx / 24, kc = (idx % 24) * 8;
        const int grow = r0 + row;
        bf16x8 val = {};
        if (grow < M) val = *(const bf16x8*)(Ab + (size_t)grow * K + kp * 192 + kc);
        *(bf16x8*)(&As[row * SA + kc]) = val;
      }
    } else {
      const float* A = (const float*)Ain;
      const int row = tid >> 2, part = tid & 3;
      const int grow = r0 + row;
      const int cbase = part * 48;
#pragma unroll
      for (int j = 0; j < 12; ++j) {
        float4 t = make_float4(0.f, 0.f, 0.f, 0.f);
        if (grow < M) t = *(const float4*)(A + (size_t)grow * K + kp * 192 + cbase + j * 4);
        bf16x4 o;
        o[0] = (__bf16)t.x; o[1] = (__bf16)t.y; o[2] = (__bf16)t.z; o[3] = (__bf16)t.w;
        *(bf16x4*)(&As[row * SA + cbase + j * 4]) = o;
      }
    }
    // ---- stage W (bf16) ----
#pragma unroll
    for (int it = 0; it < 6 * NT; ++it) {
      const int idx = tid + it * 256;
      const int wr = idx / 24, kc = (idx % 24) * 8;
      const int gw = col0 + wr;
      bf16x8 val = {};
      if (gw < Nvalid) val = *(const bf16x8*)(W + (size_t)gw * K + kp * 192 + kc);
      *(bf16x8*)(&Ws[wr * SA + kc]) = val;
    }
    __syncthreads();
    // ---- mfma ----
#pragma unroll
    for (int ks = 0; ks < 6; ++ks) {
      const int kb = ks * 32 + quad * 8;
      bf16x8 a0 = *(const bf16x8*)(&As[(rh * 32 + lm) * SA + kb]);
      bf16x8 a1 = *(const bf16x8*)(&As[(rh * 32 + 16 + lm) * SA + kb]);
#pragma unroll
      for (int tj = 0; tj < CT; ++tj) {
        bf16x8 bfr = *(const bf16x8*)(&Ws[(ch * (16 * CT) + tj * 16 + lm) * SA + kb]);
        acc[0][tj] = __builtin_amdgcn_mfma_f32_16x16x32_bf16(a0, bfr, acc[0][tj], 0, 0, 0);
        acc[1][tj] = __builtin_amdgcn_mfma_f32_16x16x32_bf16(a1, bfr, acc[1][tj], 0, 0, 0);
      }
    }
  }

  // ---- epilogue ----
  if constexpr (EPI == EPI_G2) {
    __shared__ float dtlS[64 * 12];
    __shared__ float wdtS[12 * 384];
#pragma unroll
    for (int ti = 0; ti < 2; ++ti)
#pragma unroll
      for (int tj = 0; tj < CT; ++tj) {
        const int colt = ch * (16 * CT) + tj * 16 + lm;
#pragma unroll
        for (int j = 0; j < 4; ++j) {
          const int rowt = rh * 32 + ti * 16 + quad * 4 + j;
          const int grow = r0 + rowt;
          const float val = acc[ti][tj][j];
          if (colt < 12) dtlS[rowt * 12 + colt] = val;
          else if (colt < 44 && grow < M)
            bcbuf[(size_t)grow * 32 + (colt - 12)] = val;
        }
      }
    for (int idx = tid; idx < 12 * 384; idx += 256) {
      const int e = idx / 12, r = idx % 12;
      wdtS[r * 384 + e] = Wdt[idx];
    }
    __syncthreads();
    for (int it = 0; it < 96; ++it) {
      const int flat = tid + it * 256;
      const int rr = flat / 384, e = flat % 384;
      const int grow = r0 + rr;
      if (grow < M) {
        float a = bdt[e];
#pragma unroll
        for (int r = 0; r < 12; ++r) a += dtlS[rr * 12 + r] * wdtS[r * 384 + e];
        dtbuf[(size_t)grow * 384 + e] = softplusf(a);
      }
    }
  } else {
#pragma unroll
    for (int ti = 0; ti < 2; ++ti)
#pragma unroll
      for (int tj = 0; tj < CT; ++tj) {
        const int colt = ch * (16 * CT) + tj * 16 + lm;
        const int gcol = col0 + colt;
        const float bv = bias[gcol];
#pragma unroll
        for (int j = 0; j < 4; ++j) {
          const int rowt = rh * 32 + ti * 16 + quad * 4 + j;
          const int grow = r0 + rowt;
          if (grow >= M) continue;
          const float val = acc[ti][tj][j] + bv;
          if constexpr (EPI == EPI_XZ) {
            O[(size_t)grow * 768 + gcol] = val;
          } else if constexpr (EPI == EPI_RES) {
            O[(size_t)grow * 192 + gcol] += val;
          } else if constexpr (EPI == EPI_RES_SKIP) {
            const float nv = O[(size_t)grow * 192 + gcol] + val;
            O[(size_t)grow * 192 + gcol] = nv;
            const int b = grow / 3136, l = grow % 3136;
            oflt[b * 602112 + gcol * 3136 + l] = nv;
          } else {  // EPI_OUT2
            const int b = grow / 784, l = grow % 784;
            oflt[b * 150528 + gcol * 784 + l] = val;
          }
        }
      }
  }
}

// ---------------- depthwise causal conv K=4 + silu, 8 outputs/thread ----------------
__global__ __launch_bounds__(256) void k_conv(
    const float* __restrict__ xz, float* __restrict__ xi,
    const float* __restrict__ cw, const float* __restrict__ cb,
    int Lseq, int nthreads)
{
  const int idx = blockIdx.x * 256 + threadIdx.x;
  if (idx >= nthreads) return;
  const int e = idx % 384;
  const int seg = idx / 384;
  const int nseg = Lseq / 8;
  const int b = seg / nseg;
  const int l0 = (seg % nseg) * 8;
  const float4 w4 = *(const float4*)(cw + e * 4);
  const float bv = cb[e];
  float xv[11];
#pragma unroll
  for (int k = 0; k < 11; ++k) {
    const int l = l0 - 3 + k;
    xv[k] = (l >= 0) ? xz[(size_t)(b * Lseq + l) * 768 + e] : 0.f;
  }
#pragma unroll
  for (int j = 0; j < 8; ++j) {
    const float a = bv + xv[j] * w4.x + xv[j + 1] * w4.y + xv[j + 2] * w4.z + xv[j + 3] * w4.w;
    xi[(size_t)(b * Lseq + l0 + j) * 384 + e] = siluf(a);
  }
}

// ======== chunked selective scan: 1 thread = 1 channel, 16 states in regs ========
constexpr int SC_LC = 56, SC_T = 8, SC_TN = 7;

__global__ __launch_bounds__(128) void k_scan1(
    const float* __restrict__ dt, const float* __restrict__ xi,
    const float* __restrict__ bc, const float* __restrict__ A_log,
    float* __restrict__ P, float* __restrict__ S, int Lseq, int NC)
{
  const int e = blockIdx.y * 128 + threadIdx.x;
  const int c = blockIdx.x % NC;
  const int b = blockIdx.x / NC;
  const int rowbase = b * Lseq + c * SC_LC;

  float An2[16];
  {
    const float4* a4 = (const float4*)(A_log + e * 16);
    float4 t0 = a4[0], t1 = a4[1], t2 = a4[2], t3 = a4[3];
    float tmp[16] = {t0.x, t0.y, t0.z, t0.w, t1.x, t1.y, t1.z, t1.w,
                     t2.x, t2.y, t2.z, t2.w, t3.x, t3.y, t3.z, t3.w};
#pragma unroll
    for (int n = 0; n < 16; ++n) An2[n] = -__expf(tmp[n]) * 1.44269504f;
  }
  float h[16], ap[16];
#pragma unroll
  for (int n = 0; n < 16; ++n) { h[n] = 0.f; ap[n] = 1.f; }

  float dA[SC_T], xA[SC_T], dB[SC_T], xB[SC_T];
  auto LOADA = [&](int t) {
#pragma unroll
    for (int j = 0; j < SC_T; ++j) {
      const size_t r = (size_t)(rowbase + t * SC_T + j) * 384 + e;
      dA[j] = dt[r]; xA[j] = xi[r];
    }
  };
  auto LOADB = [&](int t) {
#pragma unroll
    for (int j = 0; j < SC_T; ++j) {
      const size_t r = (size_t)(rowbase + t * SC_T + j) * 384 + e;
      dB[j] = dt[r]; xB[j] = xi[r];
    }
  };
  auto COMP = [&](const float (&d8)[SC_T], const float (&x8)[SC_T], int t) {
#pragma unroll
    for (int j = 0; j < SC_T; ++j) {
      const int l = t * SC_T + j;
      const float dtv = d8[j];
      const float u = dtv * x8[j];
      const float4* br = (const float4*)(bc + (size_t)(rowbase + l) * 32);
      const float4 B0 = br[0], B1 = br[1], B2 = br[2], B3 = br[3];
      const float Bv[16] = {B0.x, B0.y, B0.z, B0.w, B1.x, B1.y, B1.z, B1.w,
                            B2.x, B2.y, B2.z, B2.w, B3.x, B3.y, B3.z, B3.w};
#pragma unroll
      for (int n = 0; n < 16; ++n) {
        const float a = __builtin_amdgcn_exp2f(dtv * An2[n]);
        h[n] = a * h[n] + u * Bv[n];
        ap[n] *= a;
      }
    }
  };

  LOADA(0);
#pragma unroll
  for (int t = 0; t < SC_TN; ++t) {
    if (t & 1) { if (t + 1 < SC_TN) LOADA(t + 1); COMP(dB, xB, t); }
    else       { if (t + 1 < SC_TN) LOADB(t + 1); COMP(dA, xA, t); }
  }

  const size_t o = ((size_t)(b * NC + c) * 384 + e) * 16;
#pragma unroll
  for (int q = 0; q < 4; ++q) {
    *(float4*)(P + o + q * 4) = make_float4(ap[q*4], ap[q*4+1], ap[q*4+2], ap[q*4+3]);
    *(float4*)(S + o + q * 4) = make_float4(h[q*4], h[q*4+1], h[q*4+2], h[q*4+3]);
  }
}

__global__ __launch_bounds__(256) void k_carry(
    const float* __restrict__ P, float* __restrict__ SH, int NC)
{
  const int tid = blockIdx.x * 256 + threadIdx.x;   // 12288
  const int b = tid / 6144, r = tid % 6144;
  size_t o = (size_t)b * NC * 6144 + r;
  float h = 0.f;
  float p = P[o], s = SH[o];
  for (int c = 0; c < NC; ++c) {
    float pn = 0.f, sn = 0.f;
    if (c + 1 < NC) { pn = P[o + 6144]; sn = SH[o + 6144]; }
    SH[o] = h;
    h = p * h + s;
    p = pn; s = sn; o += 6144;
  }
}

__global__ __launch_bounds__(128) void k_scan2(
    const float* __restrict__ dt, const float* __restrict__ xi,
    const float* __restrict__ bc, const float* __restrict__ xz,
    const float* __restrict__ A_log, const float* __restrict__ Dskip,
    const float* __restrict__ H0, __bf16* __restrict__ y, int Lseq, int NC)
{
  const int e = blockIdx.y * 128 + threadIdx.x;
  const int c = blockIdx.x % NC;
  const int b = blockIdx.x / NC;
  const int rowbase = b * Lseq + c * SC_LC;

  float An2[16];
  {
    const float4* a4 = (const float4*)(A_log + e * 16);
    float4 t0 = a4[0], t1 = a4[1], t2 = a4[2], t3 = a4[3];
    float tmp[16] = {t0.x, t0.y, t0.z, t0.w, t1.x, t1.y, t1.z, t1.w,
                     t2.x, t2.y, t2.z, t2.w, t3.x, t3.y, t3.z, t3.w};
#pragma unroll
    for (int n = 0; n < 16; ++n) An2[n] = -__expf(tmp[n]) * 1.44269504f;
  }
  float h[16];
  {
    const size_t o = ((size_t)(b * NC + c) * 384 + e) * 16;
    const float4* h4 = (const float4*)(H0 + o);
    float4 t0 = h4[0], t1 = h4[1], t2 = h4[2], t3 = h4[3];
    h[0]=t0.x; h[1]=t0.y; h[2]=t0.z; h[3]=t0.w;
    h[4]=t1.x; h[5]=t1.y; h[6]=t1.z; h[7]=t1.w;
    h[8]=t2.x; h[9]=t2.y; h[10]=t2.z; h[11]=t2.w;
    h[12]=t3.x; h[13]=t3.y; h[14]=t3.z; h[15]=t3.w;
  }
  const float Dse = Dskip[e];

  float dA[SC_T], xA[SC_T], zA[SC_T], dB[SC_T], xB[SC_T], zB[SC_T];
  auto LOADA = [&](int t) {
#pragma unroll
    for (int j = 0; j < SC_T; ++j) {
      const size_t r = (size_t)(rowbase + t * SC_T + j);
      dA[j] = dt[r * 384 + e]; xA[j] = xi[r * 384 + e];
      zA[j] = xz[r * 768 + 384 + e];
    }
  };
  auto LOADB = [&](int t) {
#pragma unroll
    for (int j = 0; j < SC_T; ++j) {
      const size_t r = (size_t)(rowbase + t * SC_T + j);
      dB[j] = dt[r * 384 + e]; xB[j] = xi[r * 384 + e];
      zB[j] = xz[r * 768 + 384 + e];
    }
  };
  auto COMP = [&](const float (&d8)[SC_T], const float (&x8)[SC_T],
                  const float (&z8)[SC_T], int t) {
#pragma unroll
    for (int j = 0; j < SC_T; ++j) {
      const int l = t * SC_T + j;
      const float dtv = d8[j];
      const float xiv = x8[j];
      const float u = dtv * xiv;
      const float4* br = (const float4*)(bc + (size_t)(rowbase + l) * 32);
      const float4 B0 = br[0], B1 = br[1], B2 = br[2], B3 = br[3];
      const float4 C0 = br[4], C1 = br[5], C2 = br[6], C3 = br[7];
      const float Bv[16] = {B0.x, B0.y, B0.z, B0.w, B1.x, B1.y, B1.z, B1.w,
                            B2.x, B2.y, B2.z, B2.w, B3.x, B3.y, B3.z, B3.w};
      const float Cv[16] = {C0.x, C0.y, C0.z, C0.w, C1.x, C1.y, C1.z, C1.w,
                            C2.x, C2.y, C2.z, C2.w, C3.x, C3.y, C3.z, C3.w};
      float yv = 0.f;
#pragma unroll
      for (int n = 0; n < 16; ++n) {
        const float a = __builtin_amdgcn_exp2f(dtv * An2[n]);
        h[n] = a * h[n] + u * Bv[n];
        yv += h[n] * Cv[n];
      }
      y[(size_t)(rowbase + l) * 384 + e] = (__bf16)((yv + Dse * xiv) * siluf(z8[j]));
    }
  };

  LOADA(0);
#pragma unroll
  for (int t = 0; t < SC_TN; ++t) {
    if (t & 1) { if (t + 1 < SC_TN) LOADA(t + 1); COMP(dB, xB, zB, t); }
    else       { if (t + 1 < SC_TN) LOADB(t + 1); COMP(dA, xA, zA, t); }
  }
}

extern "C" void kernel_launch(void* const* d_in, const int* in_sizes, int n_in,
                              void* d_out, int out_size, void* d_ws, size_t ws_size,
                              hipStream_t stream)
{
  const float* x    = (const float*)d_in[0];
  const float* pw   = (const float*)d_in[1];
  const float* pb   = (const float*)d_in[2];
  const float* bng  = (const float*)d_in[3];
  const float* bnb  = (const float*)d_in[4];
  const float* bnm  = (const float*)d_in[5];
  const float* bnv  = (const float*)d_in[6];
  const float* lng  = (const float*)d_in[7];
  const float* lnb  = (const float*)d_in[8];
  const float* Win  = (const float*)d_in[9];
  const float* b_in = (const float*)d_in[10];
  const float* cw   = (const float*)d_in[11];
  const float* cb   = (const float*)d_in[12];
  const float* Wx   = (const float*)d_in[13];
  const float* Wdt  = (const float*)d_in[14];
  const float* bdt  = (const float*)d_in[15];
  const float* Alog = (const float*)d_in[16];
  const float* Dsk  = (const float*)d_in[17];
  const float* Wout = (const float*)d_in[18];
  const float* bout = (const float*)d_in[19];

  float* wsf = (float*)d_ws;
  float* v    = wsf;                     // 1204224
  float* xz   = v + 1204224;             // 4816896
  float* xib  = xz + 4816896;            // 2408448
  float* dtb  = xib + 2408448;           // 2408448
  float* bcb  = dtb + 2408448;           // 200704
  float* Sb   = bcb + 200704;            // 688128
  __bf16* hb  = (__bf16*)(Sb + 688128);  // 1204224 bf16 = 602112 f
  __bf16* yB  = (__bf16*)(Sb + 688128 + 602112);           // 2408448 bf16
  __bf16* Wb  = (__bf16*)(Sb + 688128 + 602112 + 1204224); // 714240 bf16

  float* out0 = (float*)d_out;
  float* out1 = out0 + 301056;
  float* Pb   = out0;  // alias: P consumed by k_carry before any output write

  k_wcvt<<<2790, 256, 0, stream>>>(Win, Wout, Wx, Wb);
  k_proj<<<dim3(98, 3), 256, 0, stream>>>(x, pw, pb, bng, bnb, bnm, bnv, v);

  for (int i = 0; i < 3; ++i) {
    const int big = (i < 2) ? 1 : 0;
    const int Lseq = big ? 3136 : 784;
    const int M = 2 * Lseq;
    const int NC = Lseq / SC_LC;     // 56 big, 14 small
    const int MB = (M + 63) / 64;
    const float* bin_i = b_in + i * 768;
    const float* cw_i  = cw + i * 384 * 4;
    const float* cb_i  = cb + i * 384;
    const float* Wdt_i = Wdt + i * 384 * 12;
    const float* bdt_i = bdt + i * 384;
    const float* Al_i  = Alog + i * 384 * 16;
    const float* Ds_i  = Dsk + i * 384;
    const float* bo_i  = bout + i * 192;
    const __bf16* Winb_i  = Wb + i * 147456;
    const __bf16* Woutb_i = Wb + 442368 + i * 73728;
    const __bf16* Wxb_i   = Wb + 663552 + i * 16896;

    if (i == 2)
      k_pool_ln<<<1568, 192, 0, stream>>>(v, lng + 2 * 192, lnb + 2 * 192, hb);
    else
      k_ln<<<1568, 256, 0, stream>>>(v, lng + i * 192, lnb + i * 192, hb);

    k_gemm<1, 2, EPI_XZ><<<dim3(MB, 6), 256, 0, stream>>>(
        hb, Winb_i, bin_i, xz, M, 192, 768,
        nullptr, nullptr, nullptr, nullptr, nullptr);
    k_conv<<<(M * 384 / 8 + 255) / 256, 256, 0, stream>>>(
        xz, xib, cw_i, cb_i, Lseq, M * 384 / 8);
    k_gemm<0, 1, EPI_G2><<<dim3(MB, 1), 256, 0, stream>>>(
        xib, Wxb_i, nullptr, nullptr, M, 384, 44,
        Wdt_i, bdt_i, dtb, bcb, nullptr);
    k_scan1<<<dim3(2 * NC, 3), 128, 0, stream>>>(dtb, xib, bcb, Al_i, Pb, Sb, Lseq, NC);
    k_carry<<<48, 256, 0, stream>>>(Pb, Sb, NC);
    k_scan2<<<dim3(2 * NC, 3), 128, 0, stream>>>(dtb, xib, bcb, xz, Al_i, Ds_i, Sb, yB, Lseq, NC);
    if (i == 0)
      k_gemm<1, 1, EPI_RES><<<dim3(MB, 3), 256, 0, stream>>>(
          yB, Woutb_i, bo_i, v, M, 384, 192,
          nullptr, nullptr, nullptr, nullptr, nullptr);
    else if (i == 1)
      k_gemm<1, 1, EPI_RES_SKIP><<<dim3(MB, 3), 256, 0, stream>>>(
          yB, Woutb_i, bo_i, v, M, 384, 192,
          nullptr, nullptr, nullptr, nullptr, out1);
    else
      k_gemm<1, 1, EPI_OUT2><<<dim3(MB, 3), 256, 0, stream>>>(
          yB, Woutb_i, bo_i, v, M, 384, 192,
          nullptr, nullptr, nullptr, nullptr, out0);
  }
}

// Round 7
// 472.381 us; speedup vs baseline: 1.2872x; 1.1434x over previous
//
#include <hip/hip_runtime.h>

typedef __attribute__((ext_vector_type(8))) __bf16 bf16x8;
typedef __attribute__((ext_vector_type(4))) __bf16 bf16x4;
typedef __attribute__((ext_vector_type(4))) float f32x4;

#define DEV static __device__ __forceinline__

DEV float fast_rcp(float x) { return __builtin_amdgcn_rcpf(x); }
DEV float sigm(float x) { return fast_rcp(1.f + __expf(-x)); }
DEV float siluf(float x) { return x * sigm(x); }
DEV float softplusf(float x) { return x > 20.f ? x : __logf(1.f + __expf(x)); }

// ---------------- weight pre-convert fp32 -> bf16 (Win | Wout | Wx concatenated) ----
__global__ __launch_bounds__(256) void k_wcvt(
    const float* __restrict__ Win, const float* __restrict__ Wout,
    const float* __restrict__ Wx, __bf16* __restrict__ Wb)
{
  const int idx = blockIdx.x * 256 + threadIdx.x;
  if (idx < 442368) Wb[idx] = (__bf16)Win[idx];
  else if (idx < 663552) Wb[idx] = (__bf16)Wout[idx - 442368];
  else if (idx < 714240) Wb[idx] = (__bf16)Wx[idx - 663552];
}

// ---------------- proj (96->192) MFMA GEMM + BN, v fp32 ----------------
__global__ __launch_bounds__(256) void k_proj(
    const float* __restrict__ x, const float* __restrict__ pw,
    const float* __restrict__ pb, const float* __restrict__ bng,
    const float* __restrict__ bnb, const float* __restrict__ bnm,
    const float* __restrict__ bnv, float* __restrict__ v)
{
  constexpr int SAP = 104;
  __shared__ __bf16 As[64 * SAP];
  __shared__ __bf16 Ws[64 * SAP];
  const int tid = threadIdx.x;
  const int r0 = blockIdx.x * 64;
  const int col0 = blockIdx.y * 64;
  const int b = r0 / 3136, l0 = r0 % 3136;
  const int lane = tid & 63, wv = tid >> 6;
  const int rh = wv >> 1, ch = wv & 1;
  const int lm = lane & 15, quad = lane >> 4;

#pragma unroll
  for (int it = 0; it < 6; ++it) {
    const int idx = tid + it * 256;       // 0..1535
    const int c = idx >> 4, l4 = idx & 15;
    const float4 t = *(const float4*)(x + ((size_t)(b * 96 + c)) * 3136 + l0 + l4 * 4);
    As[(l4 * 4 + 0) * SAP + c] = (__bf16)t.x;
    As[(l4 * 4 + 1) * SAP + c] = (__bf16)t.y;
    As[(l4 * 4 + 2) * SAP + c] = (__bf16)t.z;
    As[(l4 * 4 + 3) * SAP + c] = (__bf16)t.w;
  }
#pragma unroll
  for (int it = 0; it < 6; ++it) {
    const int idx = tid + it * 256;
    const int wr = idx / 24, kc = (idx % 24) * 4;
    const float4 t = *(const float4*)(pw + (size_t)(col0 + wr) * 96 + kc);
    bf16x4 o;
    o[0] = (__bf16)t.x; o[1] = (__bf16)t.y; o[2] = (__bf16)t.z; o[3] = (__bf16)t.w;
    *(bf16x4*)(&Ws[wr * SAP + kc]) = o;
  }
  __syncthreads();

  f32x4 acc[2][2] = {};
#pragma unroll
  for (int ks = 0; ks < 3; ++ks) {
    const int kb = ks * 32 + quad * 8;
    bf16x8 a0 = *(const bf16x8*)(&As[(rh * 32 + lm) * SAP + kb]);
    bf16x8 a1 = *(const bf16x8*)(&As[(rh * 32 + 16 + lm) * SAP + kb]);
    bf16x8 b0 = *(const bf16x8*)(&Ws[(ch * 32 + lm) * SAP + kb]);
    bf16x8 b1 = *(const bf16x8*)(&Ws[(ch * 32 + 16 + lm) * SAP + kb]);
    acc[0][0] = __builtin_amdgcn_mfma_f32_16x16x32_bf16(a0, b0, acc[0][0], 0, 0, 0);
    acc[0][1] = __builtin_amdgcn_mfma_f32_16x16x32_bf16(a0, b1, acc[0][1], 0, 0, 0);
    acc[1][0] = __builtin_amdgcn_mfma_f32_16x16x32_bf16(a1, b0, acc[1][0], 0, 0, 0);
    acc[1][1] = __builtin_amdgcn_mfma_f32_16x16x32_bf16(a1, b1, acc[1][1], 0, 0, 0);
  }

#pragma unroll
  for (int ti = 0; ti < 2; ++ti)
#pragma unroll
    for (int tj = 0; tj < 2; ++tj) {
      const int gcol = col0 + ch * 32 + tj * 16 + lm;
      const float s = rsqrtf(bnv[gcol] + 1e-5f) * bng[gcol];
      const float sh = (pb[gcol] - bnm[gcol]) * s + bnb[gcol];
#pragma unroll
      for (int j = 0; j < 4; ++j) {
        const int grow = r0 + rh * 32 + ti * 16 + quad * 4 + j;
        v[(size_t)grow * 192 + gcol] = acc[ti][tj][j] * s + sh;
      }
    }
}

// ---------------- LN over 192 -> hb bf16 ----------------
__global__ __launch_bounds__(256) void k_ln(
    const float* __restrict__ v, const float* __restrict__ lng,
    const float* __restrict__ lnb, __bf16* __restrict__ hb)
{
  const int wv = threadIdx.x >> 6, lane = threadIdx.x & 63;
  const int row = blockIdx.x * 4 + wv;
  const float* p = v + (size_t)row * 192 + lane * 3;
  float a = p[0], b = p[1], c = p[2];
  float s = a + b + c;
  float sq = a * a + b * b + c * c;
#pragma unroll
  for (int d = 1; d < 64; d <<= 1) { s += __shfl_xor(s, d); sq += __shfl_xor(sq, d); }
  const float mean = s * (1.f / 192.f);
  const float rstd = rsqrtf(sq * (1.f / 192.f) - mean * mean + 1e-5f);
  const float* g = lng + lane * 3;
  const float* bb = lnb + lane * 3;
  __bf16* o = hb + (size_t)row * 192 + lane * 3;
  o[0] = (__bf16)((a - mean) * rstd * g[0] + bb[0]);
  o[1] = (__bf16)((b - mean) * rstd * g[1] + bb[1]);
  o[2] = (__bf16)((c - mean) * rstd * g[2] + bb[2]);
}

// ---------------- 2x2 maxpool + LN -> hb bf16 (layer 2 input) ----------------
__global__ __launch_bounds__(192) void k_pool_ln(
    const float* __restrict__ v, const float* __restrict__ lng,
    const float* __restrict__ lnb, __bf16* __restrict__ hb)
{
  __shared__ float ssum[3], ssq[3];
  const int tid = threadIdx.x;
  const int pix2 = blockIdx.x;
  const int b = pix2 / 784, l2 = pix2 % 784;
  const int h2 = l2 / 28, w2 = l2 % 28;
  const float* p = v + (size_t)(b * 3136 + h2 * 112 + w2 * 2) * 192 + tid;
  const float m = fmaxf(fmaxf(p[0], p[192]), fmaxf(p[56 * 192], p[57 * 192]));
  float s = m, sq = m * m;
#pragma unroll
  for (int d = 1; d < 64; d <<= 1) { s += __shfl_xor(s, d); sq += __shfl_xor(sq, d); }
  const int wv = tid >> 6;
  if ((tid & 63) == 0) { ssum[wv] = s; ssq[wv] = sq; }
  __syncthreads();
  const float ts = ssum[0] + ssum[1] + ssum[2];
  const float tq = ssq[0] + ssq[1] + ssq[2];
  const float mean = ts * (1.f / 192.f);
  const float rstd = rsqrtf(tq * (1.f / 192.f) - mean * mean + 1e-5f);
  hb[(size_t)pix2 * 192 + tid] = (__bf16)((m - mean) * rstd * lng[tid] + lnb[tid]);
}

// ---------------- generic MFMA GEMM: O[r,e] = sum_d A[r,d]*W[e,d] ----------------
constexpr int EPI_XZ = 0, EPI_G2 = 1, EPI_RES = 2, EPI_RES_SKIP = 3, EPI_OUT2 = 4;

template <int ABF, int NT, int EPI>
__global__ __launch_bounds__(256) void k_gemm(
    const void* __restrict__ Ain, const __bf16* __restrict__ W,
    const float* __restrict__ bias, float* __restrict__ O,
    int M, int K, int Nvalid,
    const float* __restrict__ Wdt, const float* __restrict__ bdt,
    float* __restrict__ dtbuf, float* __restrict__ bcbuf,
    float* __restrict__ oflt)
{
  constexpr int SA = 200;
  constexpr int CT = (NT == 1) ? 2 : 4;
  __shared__ __bf16 As[64 * SA];
  __shared__ __bf16 Ws[64 * NT * SA];
  const int tid = threadIdx.x;
  const int r0 = blockIdx.x * 64;
  const int col0 = blockIdx.y * (64 * NT);
  const int lane = tid & 63, wv = tid >> 6;
  const int rh = (NT == 1) ? (wv >> 1) : (wv & 1);
  const int ch = (NT == 1) ? (wv & 1) : (wv >> 1);
  const int lm = lane & 15, quad = lane >> 4;

  f32x4 acc[2][CT] = {};
  const int nkp = K / 192;
  for (int kp = 0; kp < nkp; ++kp) {
    if (kp) __syncthreads();
    if constexpr (ABF == 1) {
      const __bf16* Ab = (const __bf16*)Ain;
#pragma unroll
      for (int it = 0; it < 6; ++it) {
        const int idx = tid + it * 256;
        const int row = idx / 24, kc = (idx % 24) * 8;
        const int grow = r0 + row;
        bf16x8 val = {};
        if (grow < M) val = *(const bf16x8*)(Ab + (size_t)grow * K + kp * 192 + kc);
        *(bf16x8*)(&As[row * SA + kc]) = val;
      }
    } else {
      const float* A = (const float*)Ain;
      const int row = tid >> 2, part = tid & 3;
      const int grow = r0 + row;
      const int cbase = part * 48;
#pragma unroll
      for (int j = 0; j < 12; ++j) {
        float4 t = make_float4(0.f, 0.f, 0.f, 0.f);
        if (grow < M) t = *(const float4*)(A + (size_t)grow * K + kp * 192 + cbase + j * 4);
        bf16x4 o;
        o[0] = (__bf16)t.x; o[1] = (__bf16)t.y; o[2] = (__bf16)t.z; o[3] = (__bf16)t.w;
        *(bf16x4*)(&As[row * SA + cbase + j * 4]) = o;
      }
    }
#pragma unroll
    for (int it = 0; it < 6 * NT; ++it) {
      const int idx = tid + it * 256;
      const int wr = idx / 24, kc = (idx % 24) * 8;
      const int gw = col0 + wr;
      bf16x8 val = {};
      if (gw < Nvalid) val = *(const bf16x8*)(W + (size_t)gw * K + kp * 192 + kc);
      *(bf16x8*)(&Ws[wr * SA + kc]) = val;
    }
    __syncthreads();
#pragma unroll
    for (int ks = 0; ks < 6; ++ks) {
      const int kb = ks * 32 + quad * 8;
      bf16x8 a0 = *(const bf16x8*)(&As[(rh * 32 + lm) * SA + kb]);
      bf16x8 a1 = *(const bf16x8*)(&As[(rh * 32 + 16 + lm) * SA + kb]);
#pragma unroll
      for (int tj = 0; tj < CT; ++tj) {
        bf16x8 bfr = *(const bf16x8*)(&Ws[(ch * (16 * CT) + tj * 16 + lm) * SA + kb]);
        acc[0][tj] = __builtin_amdgcn_mfma_f32_16x16x32_bf16(a0, bfr, acc[0][tj], 0, 0, 0);
        acc[1][tj] = __builtin_amdgcn_mfma_f32_16x16x32_bf16(a1, bfr, acc[1][tj], 0, 0, 0);
      }
    }
  }

  if constexpr (EPI == EPI_G2) {
    __shared__ float dtlS[64 * 12];
    __shared__ float wdtS[12 * 384];
#pragma unroll
    for (int ti = 0; ti < 2; ++ti)
#pragma unroll
      for (int tj = 0; tj < CT; ++tj) {
        const int colt = ch * (16 * CT) + tj * 16 + lm;
#pragma unroll
        for (int j = 0; j < 4; ++j) {
          const int rowt = rh * 32 + ti * 16 + quad * 4 + j;
          const int grow = r0 + rowt;
          const float val = acc[ti][tj][j];
          if (colt < 12) dtlS[rowt * 12 + colt] = val;
          else if (colt < 44 && grow < M)
            bcbuf[(size_t)grow * 32 + (colt - 12)] = val;
        }
      }
    for (int idx = tid; idx < 12 * 384; idx += 256) {
      const int e = idx / 12, r = idx % 12;
      wdtS[r * 384 + e] = Wdt[idx];
    }
    __syncthreads();
    for (int it = 0; it < 96; ++it) {
      const int flat = tid + it * 256;
      const int rr = flat / 384, e = flat % 384;
      const int grow = r0 + rr;
      if (grow < M) {
        float a = bdt[e];
#pragma unroll
        for (int r = 0; r < 12; ++r) a += dtlS[rr * 12 + r] * wdtS[r * 384 + e];
        dtbuf[(size_t)grow * 384 + e] = softplusf(a);
      }
    }
  } else {
#pragma unroll
    for (int ti = 0; ti < 2; ++ti)
#pragma unroll
      for (int tj = 0; tj < CT; ++tj) {
        const int colt = ch * (16 * CT) + tj * 16 + lm;
        const int gcol = col0 + colt;
        const float bv = bias[gcol];
#pragma unroll
        for (int j = 0; j < 4; ++j) {
          const int rowt = rh * 32 + ti * 16 + quad * 4 + j;
          const int grow = r0 + rowt;
          if (grow >= M) continue;
          const float val = acc[ti][tj][j] + bv;
          if constexpr (EPI == EPI_XZ) {
            O[(size_t)grow * 768 + gcol] = val;
          } else if constexpr (EPI == EPI_RES) {
            O[(size_t)grow * 192 + gcol] += val;
          } else if constexpr (EPI == EPI_RES_SKIP) {
            const float nv = O[(size_t)grow * 192 + gcol] + val;
            O[(size_t)grow * 192 + gcol] = nv;
            const int b = grow / 3136, l = grow % 3136;
            oflt[b * 602112 + gcol * 3136 + l] = nv;
          } else {  // EPI_OUT2
            const int b = grow / 784, l = grow % 784;
            oflt[b * 150528 + gcol * 784 + l] = val;
          }
        }
      }
  }
}

// ---------------- depthwise causal conv K=4 + silu, 8 outputs/thread ----------------
__global__ __launch_bounds__(256) void k_conv(
    const float* __restrict__ xz, float* __restrict__ xi,
    const float* __restrict__ cw, const float* __restrict__ cb,
    int Lseq, int nthreads)
{
  const int idx = blockIdx.x * 256 + threadIdx.x;
  if (idx >= nthreads) return;
  const int e = idx % 384;
  const int seg = idx / 384;
  const int nseg = Lseq / 8;
  const int b = seg / nseg;
  const int l0 = (seg % nseg) * 8;
  const float4 w4 = *(const float4*)(cw + e * 4);
  const float bv = cb[e];
  float xv[11];
#pragma unroll
  for (int k = 0; k < 11; ++k) {
    const int l = l0 - 3 + k;
    xv[k] = (l >= 0) ? xz[(size_t)(b * Lseq + l) * 768 + e] : 0.f;
  }
#pragma unroll
  for (int j = 0; j < 8; ++j) {
    const float a = bv + xv[j] * w4.x + xv[j + 1] * w4.y + xv[j + 2] * w4.z + xv[j + 3] * w4.w;
    xi[(size_t)(b * Lseq + l0 + j) * 384 + e] = siluf(a);
  }
}

// ======== chunked selective scan: 1 thread = 1 channel, 16 states in regs ========
// B/C rows (block-uniform) staged in LDS to remove global latency from the recurrence.
constexpr int SC_LC = 56, SC_T = 8, SC_TN = 7;

__global__ __launch_bounds__(128) void k_scan1(
    const float* __restrict__ dt, const float* __restrict__ xi,
    const float* __restrict__ bc, const float* __restrict__ A_log,
    float* __restrict__ P, float* __restrict__ S, int Lseq, int NC)
{
  __shared__ float Bs[SC_LC * 16];
  const int e = blockIdx.y * 128 + threadIdx.x;
  const int c = blockIdx.x % NC;
  const int b = blockIdx.x / NC;
  const int rowbase = b * Lseq + c * SC_LC;

  for (int idx = threadIdx.x; idx < SC_LC * 16; idx += 128) {
    const int l = idx >> 4, q = idx & 15;
    Bs[idx] = bc[(size_t)(rowbase + l) * 32 + q];
  }

  float An2[16];
  {
    const float4* a4 = (const float4*)(A_log + e * 16);
    float4 t0 = a4[0], t1 = a4[1], t2 = a4[2], t3 = a4[3];
    float tmp[16] = {t0.x, t0.y, t0.z, t0.w, t1.x, t1.y, t1.z, t1.w,
                     t2.x, t2.y, t2.z, t2.w, t3.x, t3.y, t3.z, t3.w};
#pragma unroll
    for (int n = 0; n < 16; ++n) An2[n] = -__expf(tmp[n]) * 1.44269504f;
  }
  float h[16], ap[16];
#pragma unroll
  for (int n = 0; n < 16; ++n) { h[n] = 0.f; ap[n] = 1.f; }

  float dA[SC_T], xA[SC_T], dB[SC_T], xB[SC_T];
  auto LOADA = [&](int t) {
#pragma unroll
    for (int j = 0; j < SC_T; ++j) {
      const size_t r = (size_t)(rowbase + t * SC_T + j) * 384 + e;
      dA[j] = dt[r]; xA[j] = xi[r];
    }
  };
  auto LOADB = [&](int t) {
#pragma unroll
    for (int j = 0; j < SC_T; ++j) {
      const size_t r = (size_t)(rowbase + t * SC_T + j) * 384 + e;
      dB[j] = dt[r]; xB[j] = xi[r];
    }
  };
  auto COMP = [&](const float (&d8)[SC_T], const float (&x8)[SC_T], int t) {
#pragma unroll
    for (int j = 0; j < SC_T; ++j) {
      const int l = t * SC_T + j;
      const float dtv = d8[j];
      const float u = dtv * x8[j];
      const float* Brow = &Bs[l * 16];
#pragma unroll
      for (int n = 0; n < 16; ++n) {
        const float a = __builtin_amdgcn_exp2f(dtv * An2[n]);
        h[n] = a * h[n] + u * Brow[n];
        ap[n] *= a;
      }
    }
  };

  LOADA(0);
  __syncthreads();
#pragma unroll
  for (int t = 0; t < SC_TN; ++t) {
    if (t & 1) { if (t + 1 < SC_TN) LOADA(t + 1); COMP(dB, xB, t); }
    else       { if (t + 1 < SC_TN) LOADB(t + 1); COMP(dA, xA, t); }
  }

  const size_t o = ((size_t)(b * NC + c) * 384 + e) * 16;
#pragma unroll
  for (int q = 0; q < 4; ++q) {
    *(float4*)(P + o + q * 4) = make_float4(ap[q*4], ap[q*4+1], ap[q*4+2], ap[q*4+3]);
    *(float4*)(S + o + q * 4) = make_float4(h[q*4], h[q*4+1], h[q*4+2], h[q*4+3]);
  }
}

__global__ __launch_bounds__(256) void k_carry(
    const float* __restrict__ P, float* __restrict__ SH, int NC)
{
  const int tid = blockIdx.x * 256 + threadIdx.x;   // 12288
  const int b = tid / 6144, r = tid % 6144;
  size_t o = (size_t)b * NC * 6144 + r;
  float h = 0.f;
  for (int c0 = 0; c0 < NC; c0 += 4) {
    const int kmax = (NC - c0 < 4) ? (NC - c0) : 4;
    float p[4], s[4];
#pragma unroll
    for (int k = 0; k < 4; ++k)
      if (k < kmax) { p[k] = P[o + (size_t)k * 6144]; s[k] = SH[o + (size_t)k * 6144]; }
#pragma unroll
    for (int k = 0; k < 4; ++k)
      if (k < kmax) { SH[o + (size_t)k * 6144] = h; h = p[k] * h + s[k]; }
    o += (size_t)4 * 6144;
  }
}

__global__ __launch_bounds__(128) void k_scan2(
    const float* __restrict__ dt, const float* __restrict__ xi,
    const float* __restrict__ bc, const float* __restrict__ xz,
    const float* __restrict__ A_log, const float* __restrict__ Dskip,
    const float* __restrict__ H0, __bf16* __restrict__ y, int Lseq, int NC)
{
  __shared__ float BCs[SC_LC * 32];
  const int e = blockIdx.y * 128 + threadIdx.x;
  const int c = blockIdx.x % NC;
  const int b = blockIdx.x / NC;
  const int rowbase = b * Lseq + c * SC_LC;

  for (int idx = threadIdx.x; idx < SC_LC * 32; idx += 128)
    BCs[idx] = bc[(size_t)rowbase * 32 + idx];

  float An2[16];
  {
    const float4* a4 = (const float4*)(A_log + e * 16);
    float4 t0 = a4[0], t1 = a4[1], t2 = a4[2], t3 = a4[3];
    float tmp[16] = {t0.x, t0.y, t0.z, t0.w, t1.x, t1.y, t1.z, t1.w,
                     t2.x, t2.y, t2.z, t2.w, t3.x, t3.y, t3.z, t3.w};
#pragma unroll
    for (int n = 0; n < 16; ++n) An2[n] = -__expf(tmp[n]) * 1.44269504f;
  }
  float h[16];
  {
    const size_t o = ((size_t)(b * NC + c) * 384 + e) * 16;
    const float4* h4 = (const float4*)(H0 + o);
    float4 t0 = h4[0], t1 = h4[1], t2 = h4[2], t3 = h4[3];
    h[0]=t0.x; h[1]=t0.y; h[2]=t0.z; h[3]=t0.w;
    h[4]=t1.x; h[5]=t1.y; h[6]=t1.z; h[7]=t1.w;
    h[8]=t2.x; h[9]=t2.y; h[10]=t2.z; h[11]=t2.w;
    h[12]=t3.x; h[13]=t3.y; h[14]=t3.z; h[15]=t3.w;
  }
  const float Dse = Dskip[e];

  float dA[SC_T], xA[SC_T], zA[SC_T], dB[SC_T], xB[SC_T], zB[SC_T];
  auto LOADA = [&](int t) {
#pragma unroll
    for (int j = 0; j < SC_T; ++j) {
      const size_t r = (size_t)(rowbase + t * SC_T + j);
      dA[j] = dt[r * 384 + e]; xA[j] = xi[r * 384 + e];
      zA[j] = xz[r * 768 + 384 + e];
    }
  };
  auto LOADB = [&](int t) {
#pragma unroll
    for (int j = 0; j < SC_T; ++j) {
      const size_t r = (size_t)(rowbase + t * SC_T + j);
      dB[j] = dt[r * 384 + e]; xB[j] = xi[r * 384 + e];
      zB[j] = xz[r * 768 + 384 + e];
    }
  };
  auto COMP = [&](const float (&d8)[SC_T], const float (&x8)[SC_T],
                  const float (&z8)[SC_T], int t) {
#pragma unroll
    for (int j = 0; j < SC_T; ++j) {
      const int l = t * SC_T + j;
      const float dtv = d8[j];
      const float xiv = x8[j];
      const float u = dtv * xiv;
      const float* Brow = &BCs[l * 32];
      const float* Crow = Brow + 16;
      float yv = 0.f;
#pragma unroll
      for (int n = 0; n < 16; ++n) {
        const float a = __builtin_amdgcn_exp2f(dtv * An2[n]);
        h[n] = a * h[n] + u * Brow[n];
        yv += h[n] * Crow[n];
      }
      y[(size_t)(rowbase + l) * 384 + e] = (__bf16)((yv + Dse * xiv) * siluf(z8[j]));
    }
  };

  LOADA(0);
  __syncthreads();
#pragma unroll
  for (int t = 0; t < SC_TN; ++t) {
    if (t & 1) { if (t + 1 < SC_TN) LOADA(t + 1); COMP(dB, xB, zB, t); }
    else       { if (t + 1 < SC_TN) LOADB(t + 1); COMP(dA, xA, zA, t); }
  }
}

extern "C" void kernel_launch(void* const* d_in, const int* in_sizes, int n_in,
                              void* d_out, int out_size, void* d_ws, size_t ws_size,
                              hipStream_t stream)
{
  const float* x    = (const float*)d_in[0];
  const float* pw   = (const float*)d_in[1];
  const float* pb   = (const float*)d_in[2];
  const float* bng  = (const float*)d_in[3];
  const float* bnb  = (const float*)d_in[4];
  const float* bnm  = (const float*)d_in[5];
  const float* bnv  = (const float*)d_in[6];
  const float* lng  = (const float*)d_in[7];
  const float* lnb  = (const float*)d_in[8];
  const float* Win  = (const float*)d_in[9];
  const float* b_in = (const float*)d_in[10];
  const float* cw   = (const float*)d_in[11];
  const float* cb   = (const float*)d_in[12];
  const float* Wx   = (const float*)d_in[13];
  const float* Wdt  = (const float*)d_in[14];
  const float* bdt  = (const float*)d_in[15];
  const float* Alog = (const float*)d_in[16];
  const float* Dsk  = (const float*)d_in[17];
  const float* Wout = (const float*)d_in[18];
  const float* bout = (const float*)d_in[19];

  float* wsf = (float*)d_ws;
  float* v    = wsf;                     // 1204224
  float* xz   = v + 1204224;             // 4816896
  float* xib  = xz + 4816896;            // 2408448
  float* dtb  = xib + 2408448;           // 2408448
  float* bcb  = dtb + 2408448;           // 200704
  float* Sb   = bcb + 200704;            // 688128
  __bf16* hb  = (__bf16*)(Sb + 688128);  // 1204224 bf16 = 602112 f
  __bf16* yB  = (__bf16*)(Sb + 688128 + 602112);           // 2408448 bf16
  __bf16* Wb  = (__bf16*)(Sb + 688128 + 602112 + 1204224); // 714240 bf16

  float* out0 = (float*)d_out;
  float* out1 = out0 + 301056;
  float* Pb   = out0;  // alias: P consumed by k_carry before any output write

  k_wcvt<<<2790, 256, 0, stream>>>(Win, Wout, Wx, Wb);
  k_proj<<<dim3(98, 3), 256, 0, stream>>>(x, pw, pb, bng, bnb, bnm, bnv, v);

  for (int i = 0; i < 3; ++i) {
    const int big = (i < 2) ? 1 : 0;
    const int Lseq = big ? 3136 : 784;
    const int M = 2 * Lseq;
    const int NC = Lseq / SC_LC;     // 56 big, 14 small
    const int MB = (M + 63) / 64;
    const float* bin_i = b_in + i * 768;
    const float* cw_i  = cw + i * 384 * 4;
    const float* cb_i  = cb + i * 384;
    const float* Wdt_i = Wdt + i * 384 * 12;
    const float* bdt_i = bdt + i * 384;
    const float* Al_i  = Alog + i * 384 * 16;
    const float* Ds_i  = Dsk + i * 384;
    const float* bo_i  = bout + i * 192;
    const __bf16* Winb_i  = Wb + i * 147456;
    const __bf16* Woutb_i = Wb + 442368 + i * 73728;
    const __bf16* Wxb_i   = Wb + 663552 + i * 16896;

    if (i == 2)
      k_pool_ln<<<1568, 192, 0, stream>>>(v, lng + 2 * 192, lnb + 2 * 192, hb);
    else
      k_ln<<<1568, 256, 0, stream>>>(v, lng + i * 192, lnb + i * 192, hb);

    k_gemm<1, 2, EPI_XZ><<<dim3(MB, 6), 256, 0, stream>>>(
        hb, Winb_i, bin_i, xz, M, 192, 768,
        nullptr, nullptr, nullptr, nullptr, nullptr);
    k_conv<<<(M * 384 / 8 + 255) / 256, 256, 0, stream>>>(
        xz, xib, cw_i, cb_i, Lseq, M * 384 / 8);
    k_gemm<0, 1, EPI_G2><<<dim3(MB, 1), 256, 0, stream>>>(
        xib, Wxb_i, nullptr, nullptr, M, 384, 44,
        Wdt_i, bdt_i, dtb, bcb, nullptr);
    k_scan1<<<dim3(2 * NC, 3), 128, 0, stream>>>(dtb, xib, bcb, Al_i, Pb, Sb, Lseq, NC);
    k_carry<<<48, 256, 0, stream>>>(Pb, Sb, NC);
    k_scan2<<<dim3(2 * NC, 3), 128, 0, stream>>>(dtb, xib, bcb, xz, Al_i, Ds_i, Sb, yB, Lseq, NC);
    if (i == 0)
      k_gemm<1, 1, EPI_RES><<<dim3(MB, 3), 256, 0, stream>>>(
          yB, Woutb_i, bo_i, v, M, 384, 192,
          nullptr, nullptr, nullptr, nullptr, nullptr);
    else if (i == 1)
      k_gemm<1, 1, EPI_RES_SKIP><<<dim3(MB, 3), 256, 0, stream>>>(
          yB, Woutb_i, bo_i, v, M, 384, 192,
          nullptr, nullptr, nullptr, nullptr, out1);
    else
      k_gemm<1, 1, EPI_OUT2><<<dim3(MB, 3), 256, 0, stream>>>(
          yB, Woutb_i, bo_i, v, M, 384, 192,
          nullptr, nullptr, nullptr, nullptr, out0);
  }
}